// Round 5
// baseline (418.612 us; speedup 1.0000x reference)
//
#include <hip/hip_runtime.h>
#include <hip/hip_bf16.h>
#include <math.h>

// Problem constants
#define B_ 4
#define T_ 2048
#define E_ 768
#define H_ 6
#define D_ 128
#define M_ (B_*T_)   // 8192 rows

typedef __attribute__((ext_vector_type(8))) short short8;
typedef __attribute__((ext_vector_type(4))) float f32x4;
typedef unsigned short u16;

__device__ inline u16 f2b(float x) {
  union { float f; unsigned u; } c; c.f = x;
  unsigned r = (c.u + 0x7fff + ((c.u >> 16) & 1)) >> 16;  // RNE
  return (u16)r;
}
__device__ inline float b2f(u16 x) {
  union { unsigned u; float f; } c; c.u = ((unsigned)x) << 16;
  return c.f;
}

// ---------------------------------------------------------------------------
// K0: RoPE tables
// ---------------------------------------------------------------------------
__global__ void k_rope_tables(float* __restrict__ cosT, float* __restrict__ sinT) {
  int t = blockIdx.x;
  int j = threadIdx.x; // 0..63
  float inv = powf(10000.0f, -(float)j * (1.0f/64.0f));
  float f = (float)t * inv;
  cosT[t*64 + j] = cosf(f);
  sinT[t*64 + j] = sinf(f);
}

// ---------------------------------------------------------------------------
// K0b: f32 -> bf16 conversion (n multiple of 4)
// ---------------------------------------------------------------------------
__global__ __launch_bounds__(256) void k_f2b(const float* __restrict__ in,
                                             u16* __restrict__ outp, int n) {
  int i = (blockIdx.x*256 + threadIdx.x)*4;
  if (i >= n) return;
  float4 v = *reinterpret_cast<const float4*>(in + i);
  typedef __attribute__((ext_vector_type(4))) short short4v;
  short4v o;
  o[0] = (short)f2b(v.x); o[1] = (short)f2b(v.y);
  o[2] = (short)f2b(v.z); o[3] = (short)f2b(v.w);
  *reinterpret_cast<short4v*>(outp + i) = o;
}

// ---------------------------------------------------------------------------
// K1: bf16 MFMA GEMM. C[m][n] = sum_k A[m][k]*Bw[n][k], K=768.
// Tile 128x128, BK=64, 4 waves (2x2), wave = 64x64 = 4x4 16x16x32 frags.
// LDS: As/Bs [128 rows][64 k] bf16, 128B rows, XOR-swizzled ((row&7)<<4).
// ---------------------------------------------------------------------------
__global__ __launch_bounds__(256) void k_gemm_bf16(
    const u16* __restrict__ A, const u16* __restrict__ Bw,
    void* __restrict__ Cout, int ldc, int outBf16, int ncol0) {
  __shared__ __align__(16) u16 As[128*64];
  __shared__ __align__(16) u16 Bs[128*64];
  const int tid  = threadIdx.x;
  const int lane = tid & 63;
  const int wv   = tid >> 6;
  const int lo   = lane & 15;
  const int hi   = lane >> 4;
  const int wm   = wv >> 1;
  const int wn   = wv & 1;
  const int m0   = blockIdx.x * 128;
  const int n0   = blockIdx.y * 128;

  f32x4 acc[4][4];
  #pragma unroll
  for (int i = 0; i < 4; ++i)
    #pragma unroll
    for (int j = 0; j < 4; ++j) {
      acc[i][j][0]=0.f; acc[i][j][1]=0.f; acc[i][j][2]=0.f; acc[i][j][3]=0.f;
    }

  for (int k0 = 0; k0 < E_; k0 += 64) {
    __syncthreads();   // previous-iter frag reads done before overwrite
    #pragma unroll
    for (int i = 0; i < 4; ++i) {
      int s   = i*256 + tid;     // 0..1023
      int row = s >> 3;          // 0..127
      int sl  = s & 7;           // 16B slot in 128B row
      short8 va = *reinterpret_cast<const short8*>(
          A  + (size_t)(m0+row)*E_ + k0 + sl*8);
      short8 vb = *reinterpret_cast<const short8*>(
          Bw + (size_t)(n0+row)*E_ + k0 + sl*8);
      int ba = (row*128 + sl*16) ^ ((row & 7) << 4);
      *(short8*)((char*)As + ba) = va;
      *(short8*)((char*)Bs + ba) = vb;
    }
    __syncthreads();
    #pragma unroll
    for (int ks = 0; ks < 2; ++ks) {
      short8 af[4], bf[4];
      #pragma unroll
      for (int mi = 0; mi < 4; ++mi) {
        int row = wm*64 + mi*16 + lo;
        int ba = (row*128 + ks*64 + hi*16) ^ ((row & 7) << 4);
        af[mi] = *(const short8*)((char*)As + ba);
      }
      #pragma unroll
      for (int nf = 0; nf < 4; ++nf) {
        int row = wn*64 + nf*16 + lo;
        int ba = (row*128 + ks*64 + hi*16) ^ ((row & 7) << 4);
        bf[nf] = *(const short8*)((char*)Bs + ba);
      }
      #pragma unroll
      for (int mi = 0; mi < 4; ++mi)
        #pragma unroll
        for (int nf = 0; nf < 4; ++nf)
          acc[mi][nf] = __builtin_amdgcn_mfma_f32_16x16x32_bf16(
              af[mi], bf[nf], acc[mi][nf], 0, 0, 0);
    }
  }

  // epilogue: C row = hi*4+r (within 16), col = lo
  #pragma unroll
  for (int mi = 0; mi < 4; ++mi)
    #pragma unroll
    for (int nf = 0; nf < 4; ++nf)
      #pragma unroll
      for (int r = 0; r < 4; ++r) {
        int m = m0 + wm*64 + mi*16 + hi*4 + r;
        int n = ncol0 + n0 + wn*64 + nf*16 + lo;
        float v = acc[mi][nf][r];
        if (outBf16) ((u16*)Cout)[(size_t)m*ldc + n] = f2b(v);
        else         ((float*)Cout)[(size_t)m*ldc + n] = v;
      }
}

// ---------------------------------------------------------------------------
// K2: v-mix + rms-norm + rope (reads bf16 qkv). Outputs bf16 qn/kn/vn.
// ---------------------------------------------------------------------------
__global__ __launch_bounds__(128) void k_vmix_norm_rope(
    const u16* __restrict__ qkv, const float* __restrict__ v1,
    const float* __restrict__ lambp,
    const float* __restrict__ cosT, const float* __restrict__ sinT,
    u16* __restrict__ qn, u16* __restrict__ kn, u16* __restrict__ vn) {
  const int bt  = blockIdx.x;
  const int row = blockIdx.y;          // 0..5 q heads, 6 = k, 7 = v
  const int d   = threadIdx.x;
  const int t   = bt & (T_-1);
  const int b   = bt >> 11;
  float val = b2f(qkv[(size_t)bt*1024 + row*128 + d]);
  if (row == 7) {
    float lamb = *lambp;
    float mix = (1.0f - lamb)*val + lamb*v1[(size_t)bt*128 + d];
    vn[(size_t)bt*128 + d] = f2b(mix);
    return;
  }
  __shared__ float red[2];
  __shared__ float nbuf[128];
  float ss = val*val;
  #pragma unroll
  for (int off = 32; off > 0; off >>= 1) ss += __shfl_xor(ss, off);
  if ((threadIdx.x & 63) == 0) red[threadIdx.x >> 6] = ss;
  __syncthreads();
  float sum = red[0] + red[1];
  float r = rsqrtf(sum * (1.0f/128.0f) + 1e-6f);
  nbuf[d] = val * r;
  __syncthreads();
  int j = d & 63;
  float c = cosT[t*64 + j];
  float s = sinT[t*64 + j];
  float o = (d < 64) ? (nbuf[d]*c + nbuf[d+64]*s)
                     : (-nbuf[d-64]*s + nbuf[d]*c);
  if (row < 6) qn[((size_t)(b*H_ + row)*T_ + t)*D_ + d] = f2b(o);
  else         kn[(size_t)bt*D_ + d] = f2b(o);
}

// ---------------------------------------------------------------------------
// K2b: vn [b][t][d] -> vnt [b][d][t]  (LDS-tiled transpose, 64t x 128d tiles)
// ---------------------------------------------------------------------------
__global__ __launch_bounds__(256) void k_transpose_v(
    const u16* __restrict__ vn, u16* __restrict__ vnt) {
  __shared__ u16 tile[64][136];
  const int tid = threadIdx.x;
  const int b  = blockIdx.y;
  const int t0 = blockIdx.x * 64;
  {
    int tr = tid >> 2;           // 0..63
    int dc = (tid & 3) * 32;
    const u16* src = vn + ((size_t)(b*T_ + t0 + tr))*D_ + dc;
    #pragma unroll
    for (int j = 0; j < 4; ++j) {
      short8 v = *reinterpret_cast<const short8*>(src + j*8);
      *reinterpret_cast<short8*>(&tile[tr][dc + j*8]) = v;
    }
  }
  __syncthreads();
  {
    int dr = tid >> 1;           // 0..127
    int tc = (tid & 1) * 32;
    #pragma unroll
    for (int j = 0; j < 4; ++j) {
      short8 o;
      #pragma unroll
      for (int jj = 0; jj < 8; ++jj) o[jj] = (short)tile[tc + j*8 + jj][dr];
      *reinterpret_cast<short8*>(
          vnt + ((size_t)(b*D_ + dr))*T_ + t0 + tc + j*8) = o;
    }
  }
}

// ---------------------------------------------------------------------------
// K3: MFMA flash attention (MQA), barrier-free. One wave per 32 q-rows.
// Grid = B*H*(T/32) = 1536 one-wave blocks, big q-tiles dispatched first.
// K and V fragments loaded directly global->register (16B/lane, L2-hot).
// P transposed via wave-private swizzled LDS (no __syncthreads anywhere).
// ---------------------------------------------------------------------------
#define KVB 32
__global__ __launch_bounds__(64) void k_attn_mfma(
    const u16* __restrict__ qn, const u16* __restrict__ kn,
    const u16* __restrict__ vnt, const float* __restrict__ x,
    const float* __restrict__ Wg, u16* __restrict__ yb) {
  __shared__ __align__(16) u16 Pl[1024];   // 2KB, wave-private

  const int lane = threadIdx.x;
  const int lo   = lane & 15;
  const int hi   = lane >> 4;

  const int bid = blockIdx.x;
  const int tw  = 63 - (bid & 63);          // 32-row tile, biggest first
  const int h   = (bid >> 6) % H_;
  const int b   = bid / (64 * H_);
  const int t0w = tw * 32;

  // Q fragments: qa[qi][ks], A-layout (row = lo, k = hi*8+j within slice ks)
  short8 qa[2][4];
  const u16* qb = qn + ((size_t)(b*H_ + h)*T_ + t0w)*D_;
  #pragma unroll
  for (int qi = 0; qi < 2; ++qi)
    #pragma unroll
    for (int ks = 0; ks < 4; ++ks)
      qa[qi][ks] = *(const short8*)(qb + (size_t)(qi*16 + lo)*D_ + ks*32 + hi*8);

  f32x4 acc[2][8];
  float mrow[2][4], lrow[2][4];
  #pragma unroll
  for (int qi = 0; qi < 2; ++qi) {
    #pragma unroll
    for (int dj = 0; dj < 8; ++dj) {
      acc[qi][dj][0]=0.f; acc[qi][dj][1]=0.f; acc[qi][dj][2]=0.f; acc[qi][dj][3]=0.f;
    }
    #pragma unroll
    for (int r = 0; r < 4; ++r) { mrow[qi][r] = -1e30f; lrow[qi][r] = 0.f; }
  }

  const u16* kg  = kn  + (size_t)b*T_*D_;
  const u16* vgt = vnt + (size_t)b*D_*T_;

  for (int kv0 = 0; kv0 <= t0w; kv0 += KVB) {
    // ---- K fragments, direct global (B-layout: col s = kj*16+lo, k = d) ----
    short8 kb[2][4];
    #pragma unroll
    for (int kj = 0; kj < 2; ++kj)
      #pragma unroll
      for (int ks = 0; ks < 4; ++ks)
        kb[kj][ks] = *(const short8*)(
            kg + (size_t)(kv0 + kj*16 + lo)*D_ + ks*32 + hi*8);
    // ---- V fragments, direct global from V^T (col d = dj*16+lo, k = s) ----
    short8 vb[8];
    #pragma unroll
    for (int dj = 0; dj < 8; ++dj)
      vb[dj] = *(const short8*)(
          vgt + (size_t)(dj*16 + lo)*T_ + kv0 + hi*8);

    // ---- QK^T ----
    f32x4 sc[2][2];
    #pragma unroll
    for (int qi = 0; qi < 2; ++qi)
      #pragma unroll
      for (int kj = 0; kj < 2; ++kj) {
        sc[qi][kj][0]=0.f; sc[qi][kj][1]=0.f; sc[qi][kj][2]=0.f; sc[qi][kj][3]=0.f;
      }
    #pragma unroll
    for (int kj = 0; kj < 2; ++kj)
      #pragma unroll
      for (int qi = 0; qi < 2; ++qi)
        #pragma unroll
        for (int ks = 0; ks < 4; ++ks)
          sc[qi][kj] = __builtin_amdgcn_mfma_f32_16x16x32_bf16(
              qa[qi][ks], kb[kj][ks], sc[qi][kj], 0, 0, 0);

    // ---- online softmax (C layout: q-row = hi*4+r, s-col = lo) ----
    const bool needmask = (kv0 + KVB - 1 > t0w);
    float p[2][2][4];
    #pragma unroll
    for (int qi = 0; qi < 2; ++qi) {
      #pragma unroll
      for (int r = 0; r < 4; ++r) {
        float s0 = sc[qi][0][r]*0.1f, s1 = sc[qi][1][r]*0.1f;
        if (needmask) {
          int row = t0w + qi*16 + hi*4 + r;
          s0 = (kv0 + lo      <= row) ? s0 : -1e30f;
          s1 = (kv0 + 16 + lo <= row) ? s1 : -1e30f;
        }
        float mx = fmaxf(s0, s1);
        mx = fmaxf(mx, __shfl_xor(mx, 1));
        mx = fmaxf(mx, __shfl_xor(mx, 2));
        mx = fmaxf(mx, __shfl_xor(mx, 4));
        mx = fmaxf(mx, __shfl_xor(mx, 8));
        float mo = mrow[qi][r];
        float mn = fmaxf(mo, mx);
        float scale = __expf(mo - mn);
        float p0 = __expf(s0 - mn);
        float p1 = __expf(s1 - mn);
        mrow[qi][r] = mn;
        lrow[qi][r] = lrow[qi][r]*scale + p0 + p1;
        p[qi][0][r] = p0; p[qi][1][r] = p1;
        #pragma unroll
        for (int dj = 0; dj < 8; ++dj) acc[qi][dj][r] *= scale;
      }
    }

    // ---- P transpose via wave-private swizzled LDS (in-order, no barrier) ----
    #pragma unroll
    for (int qi = 0; qi < 2; ++qi)
      #pragma unroll
      for (int kj = 0; kj < 2; ++kj)
        #pragma unroll
        for (int r = 0; r < 4; ++r) {
          int row = qi*16 + hi*4 + r;
          int col = kj*16 + lo;
          int ba = (row*64 + col*2) ^ ((row & 7) << 4);
          *(u16*)((char*)Pl + ba) = f2b(p[qi][kj][r]);
        }
    short8 pa[2];
    #pragma unroll
    for (int qi = 0; qi < 2; ++qi) {
      int row = qi*16 + lo;
      int ba = (row*64 + hi*16) ^ ((row & 7) << 4);
      pa[qi] = *(const short8*)((char*)Pl + ba);
    }
    // ---- PV ----
    #pragma unroll
    for (int dj = 0; dj < 8; ++dj)
      #pragma unroll
      for (int qi = 0; qi < 2; ++qi)
        acc[qi][dj] = __builtin_amdgcn_mfma_f32_16x16x32_bf16(
            pa[qi], vb[dj], acc[qi][dj], 0, 0, 0);
  }

  // ---- epilogue: reduce l, gate, write yb ----
  #pragma unroll
  for (int qi = 0; qi < 2; ++qi)
    #pragma unroll
    for (int r = 0; r < 4; ++r) {
      float lv = lrow[qi][r];
      lv += __shfl_xor(lv, 1);
      lv += __shfl_xor(lv, 2);
      lv += __shfl_xor(lv, 4);
      lv += __shfl_xor(lv, 8);
      lrow[qi][r] = lv;
    }
  #pragma unroll
  for (int qi = 0; qi < 2; ++qi)
    #pragma unroll
    for (int r = 0; r < 4; ++r) {
      int trow = t0w + qi*16 + hi*4 + r;
      size_t bt = (size_t)b*T_ + trow;
      float dotg = 0.f;
      #pragma unroll
      for (int jj = 0; jj < 12; ++jj)
        dotg += x[bt*E_ + jj]*Wg[h*12 + jj];
      float g = 1.f/(1.f + __expf(-dotg));
      float coef = g / lrow[qi][r];
      #pragma unroll
      for (int dj = 0; dj < 8; ++dj)
        yb[bt*E_ + h*D_ + dj*16 + lo] = f2b(acc[qi][dj][r]*coef);
    }
}

// ---------------------------------------------------------------------------
extern "C" void kernel_launch(void* const* d_in, const int* in_sizes, int n_in,
                              void* d_out, int out_size, void* d_ws, size_t ws_size,
                              hipStream_t stream) {
  const float* x    = (const float*)d_in[0];
  const float* v1   = (const float*)d_in[1];
  const float* Wq   = (const float*)d_in[2];
  const float* Wk   = (const float*)d_in[3];
  const float* Wv   = (const float*)d_in[4];
  const float* lamb = (const float*)d_in[5];
  const float* Wo   = (const float*)d_in[6];
  const float* Wg   = (const float*)d_in[7];
  float* out = (float*)d_out;

  // workspace layout (u16 units for bf16 buffers)
  u16* xb   = (u16*)d_ws;
  u16* qkvb = xb   + (size_t)M_*E_;        // 8192*1024
  u16* qn   = qkvb + (size_t)M_*1024;
  u16* kn   = qn   + (size_t)M_*E_;
  u16* vn   = kn   + (size_t)M_*D_;
  u16* vnt  = vn   + (size_t)M_*D_;
  u16* yb   = vnt  + (size_t)M_*D_;
  u16* Wqb  = yb   + (size_t)M_*E_;
  u16* Wkb  = Wqb  + (size_t)E_*E_;
  u16* Wvb  = Wkb  + (size_t)D_*E_;
  u16* Wob  = Wvb  + (size_t)D_*E_;
  float* cosT = (float*)(Wob + (size_t)E_*E_);
  float* sinT = cosT + T_*64;

  k_rope_tables<<<T_, 64, 0, stream>>>(cosT, sinT);

  k_f2b<<<(M_*E_/4 + 255)/256, 256, 0, stream>>>(x,  xb,  M_*E_);
  k_f2b<<<(E_*E_/4 + 255)/256, 256, 0, stream>>>(Wq, Wqb, E_*E_);
  k_f2b<<<(D_*E_/4 + 255)/256, 256, 0, stream>>>(Wk, Wkb, D_*E_);
  k_f2b<<<(D_*E_/4 + 255)/256, 256, 0, stream>>>(Wv, Wvb, D_*E_);
  k_f2b<<<(E_*E_/4 + 255)/256, 256, 0, stream>>>(Wo, Wob, E_*E_);

  k_gemm_bf16<<<dim3(M_/128, 6), 256, 0, stream>>>(xb, Wqb, qkvb, 1024, 1, 0);
  k_gemm_bf16<<<dim3(M_/128, 1), 256, 0, stream>>>(xb, Wkb, qkvb, 1024, 1, 768);
  k_gemm_bf16<<<dim3(M_/128, 1), 256, 0, stream>>>(xb, Wvb, qkvb, 1024, 1, 896);

  k_vmix_norm_rope<<<dim3(M_, 8), 128, 0, stream>>>(qkvb, v1, lamb, cosT, sinT,
                                                    qn, kn, vn);
  k_transpose_v<<<dim3(T_/64, B_), 256, 0, stream>>>(vn, vnt);

  k_attn_mfma<<<B_*H_*(T_/32), 64, 0, stream>>>(qn, kn, vnt, x, Wg, yb);

  k_gemm_bf16<<<dim3(M_/128, 6), 256, 0, stream>>>(yb, Wob, out, 768, 0, 0);

  hipMemcpyAsync(out + (size_t)M_*E_, v1, (size_t)M_*D_*sizeof(float),
                 hipMemcpyDeviceToDevice, stream);
}

// Round 6
// 315.828 us; speedup vs baseline: 1.3254x; 1.3254x over previous
//
#include <hip/hip_runtime.h>
#include <hip/hip_bf16.h>
#include <math.h>

// Problem constants
#define B_ 4
#define T_ 2048
#define E_ 768
#define H_ 6
#define D_ 128
#define M_ (B_*T_)   // 8192 rows

typedef __attribute__((ext_vector_type(8))) short short8;
typedef __attribute__((ext_vector_type(4))) float f32x4;
typedef unsigned short u16;

__device__ inline u16 f2b(float x) {
  union { float f; unsigned u; } c; c.f = x;
  unsigned r = (c.u + 0x7fff + ((c.u >> 16) & 1)) >> 16;  // RNE
  return (u16)r;
}
__device__ inline float b2f(u16 x) {
  union { unsigned u; float f; } c; c.u = ((unsigned)x) << 16;
  return c.f;
}

// ---------------------------------------------------------------------------
// K0: RoPE tables
// ---------------------------------------------------------------------------
__global__ void k_rope_tables(float* __restrict__ cosT, float* __restrict__ sinT) {
  int t = blockIdx.x;
  int j = threadIdx.x; // 0..63
  float inv = powf(10000.0f, -(float)j * (1.0f/64.0f));
  float f = (float)t * inv;
  cosT[t*64 + j] = cosf(f);
  sinT[t*64 + j] = sinf(f);
}

// ---------------------------------------------------------------------------
// K0b: f32 -> bf16 conversion (n multiple of 4)
// ---------------------------------------------------------------------------
__global__ __launch_bounds__(256) void k_f2b(const float* __restrict__ in,
                                             u16* __restrict__ outp, int n) {
  int i = (blockIdx.x*256 + threadIdx.x)*4;
  if (i >= n) return;
  float4 v = *reinterpret_cast<const float4*>(in + i);
  typedef __attribute__((ext_vector_type(4))) short short4v;
  short4v o;
  o[0] = (short)f2b(v.x); o[1] = (short)f2b(v.y);
  o[2] = (short)f2b(v.z); o[3] = (short)f2b(v.w);
  *reinterpret_cast<short4v*>(outp + i) = o;
}

// ---------------------------------------------------------------------------
// K1: bf16 MFMA GEMM. C[m][n] = sum_k A[m][k]*Bw[n][k], K=768.
// Tile 128x128, BK=64, 4 waves (2x2), wave = 64x64 = 4x4 16x16x32 frags.
// LDS: As/Bs [128 rows][64 k] bf16, 128B rows, XOR-swizzled ((row&7)<<4).
// ---------------------------------------------------------------------------
__global__ __launch_bounds__(256) void k_gemm_bf16(
    const u16* __restrict__ A, const u16* __restrict__ Bw,
    void* __restrict__ Cout, int ldc, int outBf16, int ncol0) {
  __shared__ __align__(16) u16 As[128*64];
  __shared__ __align__(16) u16 Bs[128*64];
  const int tid  = threadIdx.x;
  const int lane = tid & 63;
  const int wv   = tid >> 6;
  const int lo   = lane & 15;
  const int hi   = lane >> 4;
  const int wm   = wv >> 1;
  const int wn   = wv & 1;
  const int m0   = blockIdx.x * 128;
  const int n0   = blockIdx.y * 128;

  f32x4 acc[4][4];
  #pragma unroll
  for (int i = 0; i < 4; ++i)
    #pragma unroll
    for (int j = 0; j < 4; ++j) {
      acc[i][j][0]=0.f; acc[i][j][1]=0.f; acc[i][j][2]=0.f; acc[i][j][3]=0.f;
    }

  for (int k0 = 0; k0 < E_; k0 += 64) {
    __syncthreads();   // previous-iter frag reads done before overwrite
    #pragma unroll
    for (int i = 0; i < 4; ++i) {
      int s   = i*256 + tid;     // 0..1023
      int row = s >> 3;          // 0..127
      int sl  = s & 7;           // 16B slot in 128B row
      short8 va = *reinterpret_cast<const short8*>(
          A  + (size_t)(m0+row)*E_ + k0 + sl*8);
      short8 vb = *reinterpret_cast<const short8*>(
          Bw + (size_t)(n0+row)*E_ + k0 + sl*8);
      int ba = (row*128 + sl*16) ^ ((row & 7) << 4);
      *(short8*)((char*)As + ba) = va;
      *(short8*)((char*)Bs + ba) = vb;
    }
    __syncthreads();
    #pragma unroll
    for (int ks = 0; ks < 2; ++ks) {
      short8 af[4], bf[4];
      #pragma unroll
      for (int mi = 0; mi < 4; ++mi) {
        int row = wm*64 + mi*16 + lo;
        int ba = (row*128 + ks*64 + hi*16) ^ ((row & 7) << 4);
        af[mi] = *(const short8*)((char*)As + ba);
      }
      #pragma unroll
      for (int nf = 0; nf < 4; ++nf) {
        int row = wn*64 + nf*16 + lo;
        int ba = (row*128 + ks*64 + hi*16) ^ ((row & 7) << 4);
        bf[nf] = *(const short8*)((char*)Bs + ba);
      }
      #pragma unroll
      for (int mi = 0; mi < 4; ++mi)
        #pragma unroll
        for (int nf = 0; nf < 4; ++nf)
          acc[mi][nf] = __builtin_amdgcn_mfma_f32_16x16x32_bf16(
              af[mi], bf[nf], acc[mi][nf], 0, 0, 0);
    }
  }

  // epilogue: C row = hi*4+r (within 16), col = lo
  #pragma unroll
  for (int mi = 0; mi < 4; ++mi)
    #pragma unroll
    for (int nf = 0; nf < 4; ++nf)
      #pragma unroll
      for (int r = 0; r < 4; ++r) {
        int m = m0 + wm*64 + mi*16 + hi*4 + r;
        int n = ncol0 + n0 + wn*64 + nf*16 + lo;
        float v = acc[mi][nf][r];
        if (outBf16) ((u16*)Cout)[(size_t)m*ldc + n] = f2b(v);
        else         ((float*)Cout)[(size_t)m*ldc + n] = v;
      }
}

// ---------------------------------------------------------------------------
// K2: v-mix + rms-norm + rope (reads bf16 qkv). Outputs bf16 qn/kn/vn.
// ---------------------------------------------------------------------------
__global__ __launch_bounds__(128) void k_vmix_norm_rope(
    const u16* __restrict__ qkv, const float* __restrict__ v1,
    const float* __restrict__ lambp,
    const float* __restrict__ cosT, const float* __restrict__ sinT,
    u16* __restrict__ qn, u16* __restrict__ kn, u16* __restrict__ vn) {
  const int bt  = blockIdx.x;
  const int row = blockIdx.y;          // 0..5 q heads, 6 = k, 7 = v
  const int d   = threadIdx.x;
  const int t   = bt & (T_-1);
  const int b   = bt >> 11;
  float val = b2f(qkv[(size_t)bt*1024 + row*128 + d]);
  if (row == 7) {
    float lamb = *lambp;
    float mix = (1.0f - lamb)*val + lamb*v1[(size_t)bt*128 + d];
    vn[(size_t)bt*128 + d] = f2b(mix);
    return;
  }
  __shared__ float red[2];
  __shared__ float nbuf[128];
  float ss = val*val;
  #pragma unroll
  for (int off = 32; off > 0; off >>= 1) ss += __shfl_xor(ss, off);
  if ((threadIdx.x & 63) == 0) red[threadIdx.x >> 6] = ss;
  __syncthreads();
  float sum = red[0] + red[1];
  float r = rsqrtf(sum * (1.0f/128.0f) + 1e-6f);
  nbuf[d] = val * r;
  __syncthreads();
  int j = d & 63;
  float c = cosT[t*64 + j];
  float s = sinT[t*64 + j];
  float o = (d < 64) ? (nbuf[d]*c + nbuf[d+64]*s)
                     : (-nbuf[d-64]*s + nbuf[d]*c);
  if (row < 6) qn[((size_t)(b*H_ + row)*T_ + t)*D_ + d] = f2b(o);
  else         kn[(size_t)bt*D_ + d] = f2b(o);
}

// ---------------------------------------------------------------------------
// K2b: vn [b][t][d] -> vnt [b][d][t]  (LDS-tiled transpose, 64t x 128d tiles)
// ---------------------------------------------------------------------------
__global__ __launch_bounds__(256) void k_transpose_v(
    const u16* __restrict__ vn, u16* __restrict__ vnt) {
  __shared__ u16 tile[64][136];
  const int tid = threadIdx.x;
  const int b  = blockIdx.y;
  const int t0 = blockIdx.x * 64;
  {
    int tr = tid >> 2;           // 0..63
    int dc = (tid & 3) * 32;
    const u16* src = vn + ((size_t)(b*T_ + t0 + tr))*D_ + dc;
    #pragma unroll
    for (int j = 0; j < 4; ++j) {
      short8 v = *reinterpret_cast<const short8*>(src + j*8);
      *reinterpret_cast<short8*>(&tile[tr][dc + j*8]) = v;
    }
  }
  __syncthreads();
  {
    int dr = tid >> 1;           // 0..127
    int tc = (tid & 1) * 32;
    #pragma unroll
    for (int j = 0; j < 4; ++j) {
      short8 o;
      #pragma unroll
      for (int jj = 0; jj < 8; ++jj) o[jj] = (short)tile[tc + j*8 + jj][dr];
      *reinterpret_cast<short8*>(
          vnt + ((size_t)(b*D_ + dr))*T_ + t0 + tc + j*8) = o;
    }
  }
}

// ---------------------------------------------------------------------------
// K3: MFMA flash attention (MQA), barrier-free, FIXED-MAX softmax.
// RMS-norm bounds scores: |0.1*q.k| <= 0.1*128 = 12.8, so softmax uses the
// constant max 12.8 (shift-invariant => exact). No running max, no acc
// rescale, no cross-lane ops in the KV loop.
// Grid = 64 ranks * 24 (b,h); rank ascending => tile size descending, so the
// 24 longest blocks are bids 0..23 and spread across all 8 XCDs.
// ---------------------------------------------------------------------------
#define KVB 32
__global__ __launch_bounds__(64) void k_attn_mfma(
    const u16* __restrict__ qn, const u16* __restrict__ kn,
    const u16* __restrict__ vnt, const float* __restrict__ x,
    const float* __restrict__ Wg, u16* __restrict__ yb) {
  __shared__ __align__(16) u16 Pl[1024];   // 2KB, wave-private

  const int lane = threadIdx.x;
  const int lo   = lane & 15;
  const int hi   = lane >> 4;

  const int bid  = blockIdx.x;
  const int rank = bid / 24;           // 0..63, 0 = biggest tile
  const int bh   = bid % 24;
  const int h    = bh % H_;
  const int b    = bh / H_;
  const int t0w  = (63 - rank) * 32;

  // Q fragments: qa[qi][ks], A-layout (row = lo, k = hi*8+j within slice ks)
  short8 qa[2][4];
  const u16* qb = qn + ((size_t)(b*H_ + h)*T_ + t0w)*D_;
  #pragma unroll
  for (int qi = 0; qi < 2; ++qi)
    #pragma unroll
    for (int ks = 0; ks < 4; ++ks)
      qa[qi][ks] = *(const short8*)(qb + (size_t)(qi*16 + lo)*D_ + ks*32 + hi*8);

  f32x4 acc[2][8];
  float lrow[2][4];
  #pragma unroll
  for (int qi = 0; qi < 2; ++qi) {
    #pragma unroll
    for (int dj = 0; dj < 8; ++dj) {
      acc[qi][dj][0]=0.f; acc[qi][dj][1]=0.f; acc[qi][dj][2]=0.f; acc[qi][dj][3]=0.f;
    }
    #pragma unroll
    for (int r = 0; r < 4; ++r) lrow[qi][r] = 0.f;
  }

  const u16* kg  = kn  + (size_t)b*T_*D_;
  const u16* vgt = vnt + (size_t)b*D_*T_;

  for (int kv0 = 0; kv0 <= t0w; kv0 += KVB) {
    // ---- K fragments, direct global (B-layout: col s = kj*16+lo, k = d) ----
    short8 kb[2][4];
    #pragma unroll
    for (int kj = 0; kj < 2; ++kj)
      #pragma unroll
      for (int ks = 0; ks < 4; ++ks)
        kb[kj][ks] = *(const short8*)(
            kg + (size_t)(kv0 + kj*16 + lo)*D_ + ks*32 + hi*8);
    // ---- V fragments, direct global from V^T (col d = dj*16+lo, k = s) ----
    short8 vb[8];
    #pragma unroll
    for (int dj = 0; dj < 8; ++dj)
      vb[dj] = *(const short8*)(
          vgt + (size_t)(dj*16 + lo)*T_ + kv0 + hi*8);

    // ---- QK^T ----
    f32x4 sc[2][2];
    #pragma unroll
    for (int qi = 0; qi < 2; ++qi)
      #pragma unroll
      for (int kj = 0; kj < 2; ++kj) {
        sc[qi][kj][0]=0.f; sc[qi][kj][1]=0.f; sc[qi][kj][2]=0.f; sc[qi][kj][3]=0.f;
      }
    #pragma unroll
    for (int kj = 0; kj < 2; ++kj)
      #pragma unroll
      for (int qi = 0; qi < 2; ++qi)
        #pragma unroll
        for (int ks = 0; ks < 4; ++ks)
          sc[qi][kj] = __builtin_amdgcn_mfma_f32_16x16x32_bf16(
              qa[qi][ks], kb[kj][ks], sc[qi][kj], 0, 0, 0);

    // ---- fixed-max softmax: p = exp(s*0.1 - 12.8), per-lane only ----
    const bool dm = (kv0 == t0w);    // only the diagonal tile needs masking
    float p[2][2][4];
    #pragma unroll
    for (int qi = 0; qi < 2; ++qi) {
      #pragma unroll
      for (int r = 0; r < 4; ++r) {
        float p0 = __expf(fmaf(sc[qi][0][r], 0.1f, -12.8f));
        float p1 = __expf(fmaf(sc[qi][1][r], 0.1f, -12.8f));
        if (dm) {
          int row = t0w + qi*16 + hi*4 + r;
          p0 = (kv0 + lo      <= row) ? p0 : 0.f;
          p1 = (kv0 + 16 + lo <= row) ? p1 : 0.f;
        }
        lrow[qi][r] += p0 + p1;
        p[qi][0][r] = p0; p[qi][1][r] = p1;
      }
    }

    // ---- P transpose via wave-private swizzled LDS (in-order, no barrier) ----
    #pragma unroll
    for (int qi = 0; qi < 2; ++qi)
      #pragma unroll
      for (int kj = 0; kj < 2; ++kj)
        #pragma unroll
        for (int r = 0; r < 4; ++r) {
          int row = qi*16 + hi*4 + r;
          int col = kj*16 + lo;
          int ba = (row*64 + col*2) ^ ((row & 7) << 4);
          *(u16*)((char*)Pl + ba) = f2b(p[qi][kj][r]);
        }
    short8 pa[2];
    #pragma unroll
    for (int qi = 0; qi < 2; ++qi) {
      int row = qi*16 + lo;
      int ba = (row*64 + hi*16) ^ ((row & 7) << 4);
      pa[qi] = *(const short8*)((char*)Pl + ba);
    }
    // ---- PV (no rescale ever — fixed max) ----
    #pragma unroll
    for (int dj = 0; dj < 8; ++dj)
      #pragma unroll
      for (int qi = 0; qi < 2; ++qi)
        acc[qi][dj] = __builtin_amdgcn_mfma_f32_16x16x32_bf16(
            pa[qi], vb[dj], acc[qi][dj], 0, 0, 0);
  }

  // ---- epilogue: reduce l across the 16 lo-lanes, gate, write yb ----
  #pragma unroll
  for (int qi = 0; qi < 2; ++qi)
    #pragma unroll
    for (int r = 0; r < 4; ++r) {
      float lv = lrow[qi][r];
      lv += __shfl_xor(lv, 1);
      lv += __shfl_xor(lv, 2);
      lv += __shfl_xor(lv, 4);
      lv += __shfl_xor(lv, 8);
      lrow[qi][r] = lv;
    }
  #pragma unroll
  for (int qi = 0; qi < 2; ++qi)
    #pragma unroll
    for (int r = 0; r < 4; ++r) {
      int trow = t0w + qi*16 + hi*4 + r;
      size_t bt = (size_t)b*T_ + trow;
      float dotg = 0.f;
      #pragma unroll
      for (int jj = 0; jj < 12; ++jj)
        dotg += x[bt*E_ + jj]*Wg[h*12 + jj];
      float g = 1.f/(1.f + __expf(-dotg));
      float coef = g / lrow[qi][r];
      #pragma unroll
      for (int dj = 0; dj < 8; ++dj)
        yb[bt*E_ + h*D_ + dj*16 + lo] = f2b(acc[qi][dj][r]*coef);
    }
}

// ---------------------------------------------------------------------------
extern "C" void kernel_launch(void* const* d_in, const int* in_sizes, int n_in,
                              void* d_out, int out_size, void* d_ws, size_t ws_size,
                              hipStream_t stream) {
  const float* x    = (const float*)d_in[0];
  const float* v1   = (const float*)d_in[1];
  const float* Wq   = (const float*)d_in[2];
  const float* Wk   = (const float*)d_in[3];
  const float* Wv   = (const float*)d_in[4];
  const float* lamb = (const float*)d_in[5];
  const float* Wo   = (const float*)d_in[6];
  const float* Wg   = (const float*)d_in[7];
  float* out = (float*)d_out;

  // workspace layout (u16 units for bf16 buffers)
  u16* xb   = (u16*)d_ws;
  u16* qkvb = xb   + (size_t)M_*E_;        // 8192*1024
  u16* qn   = qkvb + (size_t)M_*1024;
  u16* kn   = qn   + (size_t)M_*E_;
  u16* vn   = kn   + (size_t)M_*D_;
  u16* vnt  = vn   + (size_t)M_*D_;
  u16* yb   = vnt  + (size_t)M_*D_;
  u16* Wqb  = yb   + (size_t)M_*E_;
  u16* Wkb  = Wqb  + (size_t)E_*E_;
  u16* Wvb  = Wkb  + (size_t)D_*E_;
  u16* Wob  = Wvb  + (size_t)D_*E_;
  float* cosT = (float*)(Wob + (size_t)E_*E_);
  float* sinT = cosT + T_*64;

  k_rope_tables<<<T_, 64, 0, stream>>>(cosT, sinT);

  k_f2b<<<(M_*E_/4 + 255)/256, 256, 0, stream>>>(x,  xb,  M_*E_);
  k_f2b<<<(E_*E_/4 + 255)/256, 256, 0, stream>>>(Wq, Wqb, E_*E_);
  k_f2b<<<(D_*E_/4 + 255)/256, 256, 0, stream>>>(Wk, Wkb, D_*E_);
  k_f2b<<<(D_*E_/4 + 255)/256, 256, 0, stream>>>(Wv, Wvb, D_*E_);
  k_f2b<<<(E_*E_/4 + 255)/256, 256, 0, stream>>>(Wo, Wob, E_*E_);

  k_gemm_bf16<<<dim3(M_/128, 6), 256, 0, stream>>>(xb, Wqb, qkvb, 1024, 1, 0);
  k_gemm_bf16<<<dim3(M_/128, 1), 256, 0, stream>>>(xb, Wkb, qkvb, 1024, 1, 768);
  k_gemm_bf16<<<dim3(M_/128, 1), 256, 0, stream>>>(xb, Wvb, qkvb, 1024, 1, 896);

  k_vmix_norm_rope<<<dim3(M_, 8), 128, 0, stream>>>(qkvb, v1, lamb, cosT, sinT,
                                                    qn, kn, vn);
  k_transpose_v<<<dim3(T_/64, B_), 256, 0, stream>>>(vn, vnt);

  k_attn_mfma<<<B_*H_*(T_/32), 64, 0, stream>>>(qn, kn, vnt, x, Wg, yb);

  k_gemm_bf16<<<dim3(M_/128, 6), 256, 0, stream>>>(yb, Wob, out, 768, 0, 0);

  hipMemcpyAsync(out + (size_t)M_*E_, v1, (size_t)M_*D_*sizeof(float),
                 hipMemcpyDeviceToDevice, stream);
}

// Round 9
// 306.370 us; speedup vs baseline: 1.3664x; 1.0309x over previous
//
#include <hip/hip_runtime.h>
#include <hip/hip_bf16.h>
#include <math.h>

// Problem constants
#define B_ 4
#define T_ 2048
#define E_ 768
#define H_ 6
#define D_ 128
#define M_ (B_*T_)   // 8192 rows

typedef __attribute__((ext_vector_type(8))) short short8;
typedef __attribute__((ext_vector_type(4))) float f32x4;
typedef unsigned short u16;
typedef unsigned int u32;

__device__ inline u16 f2b(float x) {
  union { float f; unsigned u; } c; c.f = x;
  unsigned r = (c.u + 0x7fff + ((c.u >> 16) & 1)) >> 16;  // RNE
  return (u16)r;
}
__device__ inline float b2f(u16 x) {
  union { unsigned u; float f; } c; c.u = ((unsigned)x) << 16;
  return c.f;
}

// ---------------------------------------------------------------------------
// K0: RoPE tables
// ---------------------------------------------------------------------------
__global__ void k_rope_tables(float* __restrict__ cosT, float* __restrict__ sinT) {
  int t = blockIdx.x;
  int j = threadIdx.x; // 0..63
  float inv = powf(10000.0f, -(float)j * (1.0f/64.0f));
  float f = (float)t * inv;
  cosT[t*64 + j] = cosf(f);
  sinT[t*64 + j] = sinf(f);
}

// ---------------------------------------------------------------------------
// K0b: f32 -> bf16 conversion (n multiple of 4)
// ---------------------------------------------------------------------------
__global__ __launch_bounds__(256) void k_f2b(const float* __restrict__ in,
                                             u16* __restrict__ outp, int n) {
  int i = (blockIdx.x*256 + threadIdx.x)*4;
  if (i >= n) return;
  float4 v = *reinterpret_cast<const float4*>(in + i);
  typedef __attribute__((ext_vector_type(4))) short short4v;
  short4v o;
  o[0] = (short)f2b(v.x); o[1] = (short)f2b(v.y);
  o[2] = (short)f2b(v.z); o[3] = (short)f2b(v.w);
  *reinterpret_cast<short4v*>(outp + i) = o;
}

// ---------------------------------------------------------------------------
// K1: bf16 MFMA GEMM. C[m][n] = sum_k A[m][k]*Bw[n][k], K=768.
// Tile 128x128, BK=64, 4 waves (2x2), wave = 64x64 = 4x4 16x16x32 frags.
// LDS: As/Bs [128 rows][64 k] bf16, 128B rows, XOR-swizzled ((row&7)<<4).
// ---------------------------------------------------------------------------
__global__ __launch_bounds__(256) void k_gemm_bf16(
    const u16* __restrict__ A, const u16* __restrict__ Bw,
    void* __restrict__ Cout, int ldc, int outBf16, int ncol0) {
  __shared__ __align__(16) u16 As[128*64];
  __shared__ __align__(16) u16 Bs[128*64];
  const int tid  = threadIdx.x;
  const int lane = tid & 63;
  const int wv   = tid >> 6;
  const int lo   = lane & 15;
  const int hi   = lane >> 4;
  const int wm   = wv >> 1;
  const int wn   = wv & 1;
  const int m0   = blockIdx.x * 128;
  const int n0   = blockIdx.y * 128;

  f32x4 acc[4][4];
  #pragma unroll
  for (int i = 0; i < 4; ++i)
    #pragma unroll
    for (int j = 0; j < 4; ++j) {
      acc[i][j][0]=0.f; acc[i][j][1]=0.f; acc[i][j][2]=0.f; acc[i][j][3]=0.f;
    }

  for (int k0 = 0; k0 < E_; k0 += 64) {
    __syncthreads();   // previous-iter frag reads done before overwrite
    #pragma unroll
    for (int i = 0; i < 4; ++i) {
      int s   = i*256 + tid;     // 0..1023
      int row = s >> 3;          // 0..127
      int sl  = s & 7;           // 16B slot in 128B row
      short8 va = *reinterpret_cast<const short8*>(
          A  + (size_t)(m0+row)*E_ + k0 + sl*8);
      short8 vb = *reinterpret_cast<const short8*>(
          Bw + (size_t)(n0+row)*E_ + k0 + sl*8);
      int ba = (row*128 + sl*16) ^ ((row & 7) << 4);
      *(short8*)((char*)As + ba) = va;
      *(short8*)((char*)Bs + ba) = vb;
    }
    __syncthreads();
    #pragma unroll
    for (int ks = 0; ks < 2; ++ks) {
      short8 af[4], bf[4];
      #pragma unroll
      for (int mi = 0; mi < 4; ++mi) {
        int row = wm*64 + mi*16 + lo;
        int ba = (row*128 + ks*64 + hi*16) ^ ((row & 7) << 4);
        af[mi] = *(const short8*)((char*)As + ba);
      }
      #pragma unroll
      for (int nf = 0; nf < 4; ++nf) {
        int row = wn*64 + nf*16 + lo;
        int ba = (row*128 + ks*64 + hi*16) ^ ((row & 7) << 4);
        bf[nf] = *(const short8*)((char*)Bs + ba);
      }
      #pragma unroll
      for (int mi = 0; mi < 4; ++mi)
        #pragma unroll
        for (int nf = 0; nf < 4; ++nf)
          acc[mi][nf] = __builtin_amdgcn_mfma_f32_16x16x32_bf16(
              af[mi], bf[nf], acc[mi][nf], 0, 0, 0);
    }
  }

  // epilogue: C row = hi*4+r (within 16), col = lo
  #pragma unroll
  for (int mi = 0; mi < 4; ++mi)
    #pragma unroll
    for (int nf = 0; nf < 4; ++nf)
      #pragma unroll
      for (int r = 0; r < 4; ++r) {
        int m = m0 + wm*64 + mi*16 + hi*4 + r;
        int n = ncol0 + n0 + wn*64 + nf*16 + lo;
        float v = acc[mi][nf][r];
        if (outBf16) ((u16*)Cout)[(size_t)m*ldc + n] = f2b(v);
        else         ((float*)Cout)[(size_t)m*ldc + n] = v;
      }
}

// ---------------------------------------------------------------------------
// K2: v-mix + rms-norm + rope (reads bf16 qkv). Outputs bf16 qn/kn/vn.
// ---------------------------------------------------------------------------
__global__ __launch_bounds__(128) void k_vmix_norm_rope(
    const u16* __restrict__ qkv, const float* __restrict__ v1,
    const float* __restrict__ lambp,
    const float* __restrict__ cosT, const float* __restrict__ sinT,
    u16* __restrict__ qn, u16* __restrict__ kn, u16* __restrict__ vn) {
  const int bt  = blockIdx.x;
  const int row = blockIdx.y;          // 0..5 q heads, 6 = k, 7 = v
  const int d   = threadIdx.x;
  const int t   = bt & (T_-1);
  const int b   = bt >> 11;
  float val = b2f(qkv[(size_t)bt*1024 + row*128 + d]);
  if (row == 7) {
    float lamb = *lambp;
    float mix = (1.0f - lamb)*val + lamb*v1[(size_t)bt*128 + d];
    vn[(size_t)bt*128 + d] = f2b(mix);
    return;
  }
  __shared__ float red[2];
  __shared__ float nbuf[128];
  float ss = val*val;
  #pragma unroll
  for (int off = 32; off > 0; off >>= 1) ss += __shfl_xor(ss, off);
  if ((threadIdx.x & 63) == 0) red[threadIdx.x >> 6] = ss;
  __syncthreads();
  float sum = red[0] + red[1];
  float r = rsqrtf(sum * (1.0f/128.0f) + 1e-6f);
  nbuf[d] = val * r;
  __syncthreads();
  int j = d & 63;
  float c = cosT[t*64 + j];
  float s = sinT[t*64 + j];
  float o = (d < 64) ? (nbuf[d]*c + nbuf[d+64]*s)
                     : (-nbuf[d-64]*s + nbuf[d]*c);
  if (row < 6) qn[((size_t)(b*H_ + row)*T_ + t)*D_ + d] = f2b(o);
  else         kn[(size_t)bt*D_ + d] = f2b(o);
}

// ---------------------------------------------------------------------------
// K2b: vn [b][t][d] -> vnt [b][d][t]  (LDS-tiled transpose, 64t x 128d tiles)
// ---------------------------------------------------------------------------
__global__ __launch_bounds__(256) void k_transpose_v(
    const u16* __restrict__ vn, u16* __restrict__ vnt) {
  __shared__ u16 tile[64][136];
  const int tid = threadIdx.x;
  const int b  = blockIdx.y;
  const int t0 = blockIdx.x * 64;
  {
    int tr = tid >> 2;           // 0..63
    int dc = (tid & 3) * 32;
    const u16* src = vn + ((size_t)(b*T_ + t0 + tr))*D_ + dc;
    #pragma unroll
    for (int j = 0; j < 4; ++j) {
      short8 v = *reinterpret_cast<const short8*>(src + j*8);
      *reinterpret_cast<short8*>(&tile[tr][dc + j*8]) = v;
    }
  }
  __syncthreads();
  {
    int dr = tid >> 1;           // 0..127
    int tc = (tid & 1) * 32;
    #pragma unroll
    for (int j = 0; j < 4; ++j) {
      short8 o;
      #pragma unroll
      for (int jj = 0; jj < 8; ++jj) o[jj] = (short)tile[tc + j*8 + jj][dr];
      *reinterpret_cast<short8*>(
          vnt + ((size_t)(b*D_ + dr))*T_ + t0 + tc + j*8) = o;
    }
  }
}

// ---------------------------------------------------------------------------
// K3: MFMA flash attention (MQA), fixed-max softmax, intra-block split-S.
// Block = 4 waves sharing ONE 32-row q-tile; wave w processes KV tiles
// w, w+4, w+8, ... (fixed-max => partials combine by plain summation).
// Waves 1-3 write packed-bf16 acc partials + l to LDS; wave 0 sums and
// runs the epilogue. No barriers in the KV loop itself.
// Grid = 64 ranks * 24 (b,h); rank ascending => tile size descending.
// ---------------------------------------------------------------------------
#define KVB 32
__global__ __launch_bounds__(256) void k_attn_mfma(
    const u16* __restrict__ qn, const u16* __restrict__ kn,
    const u16* __restrict__ vnt, const float* __restrict__ x,
    const float* __restrict__ Wg, u16* __restrict__ yb) {
  __shared__ __align__(16) u16 Pl[4*1024];       // per-wave P transpose, 8KB
  __shared__ u32   Pacc[3][32][64];              // packed bf16 partials, 24KB
  __shared__ float Lacc[3][32];                  // l partials

  const int tid  = threadIdx.x;
  const int lane = tid & 63;
  const int wv   = tid >> 6;
  const int lo   = lane & 15;
  const int hi   = lane >> 4;

  const int bid  = blockIdx.x;
  const int rank = bid / 24;           // 0..63, 0 = biggest tile
  const int bh   = bid % 24;
  const int h    = bh % H_;
  const int b    = bh / H_;
  const int t0w  = (63 - rank) * 32;

  // Q fragments (all 4 waves load the same q-tile; L1/L2-hot)
  short8 qa[2][4];
  const u16* qb = qn + ((size_t)(b*H_ + h)*T_ + t0w)*D_;
  #pragma unroll
  for (int qi = 0; qi < 2; ++qi)
    #pragma unroll
    for (int ks = 0; ks < 4; ++ks)
      qa[qi][ks] = *(const short8*)(qb + (size_t)(qi*16 + lo)*D_ + ks*32 + hi*8);

  f32x4 acc[2][8];
  float lrow[2][4];
  #pragma unroll
  for (int qi = 0; qi < 2; ++qi) {
    #pragma unroll
    for (int dj = 0; dj < 8; ++dj) {
      acc[qi][dj][0]=0.f; acc[qi][dj][1]=0.f; acc[qi][dj][2]=0.f; acc[qi][dj][3]=0.f;
    }
    #pragma unroll
    for (int r = 0; r < 4; ++r) lrow[qi][r] = 0.f;
  }

  const u16* kg  = kn  + (size_t)b*T_*D_;
  const u16* vgt = vnt + (size_t)b*D_*T_;

  // wave wv handles KV tiles wv, wv+4, wv+8, ...
  for (int kv0 = wv*KVB; kv0 <= t0w; kv0 += 4*KVB) {
    // ---- K fragments, direct global (B-layout: col s = kj*16+lo, k = d) ----
    short8 kb[2][4];
    #pragma unroll
    for (int kj = 0; kj < 2; ++kj)
      #pragma unroll
      for (int ks = 0; ks < 4; ++ks)
        kb[kj][ks] = *(const short8*)(
            kg + (size_t)(kv0 + kj*16 + lo)*D_ + ks*32 + hi*8);
    // ---- V fragments, direct global from V^T (col d = dj*16+lo, k = s) ----
    short8 vb[8];
    #pragma unroll
    for (int dj = 0; dj < 8; ++dj)
      vb[dj] = *(const short8*)(
          vgt + (size_t)(dj*16 + lo)*T_ + kv0 + hi*8);

    // ---- QK^T ----
    f32x4 sc[2][2];
    #pragma unroll
    for (int qi = 0; qi < 2; ++qi)
      #pragma unroll
      for (int kj = 0; kj < 2; ++kj) {
        sc[qi][kj][0]=0.f; sc[qi][kj][1]=0.f; sc[qi][kj][2]=0.f; sc[qi][kj][3]=0.f;
      }
    #pragma unroll
    for (int kj = 0; kj < 2; ++kj)
      #pragma unroll
      for (int qi = 0; qi < 2; ++qi)
        #pragma unroll
        for (int ks = 0; ks < 4; ++ks)
          sc[qi][kj] = __builtin_amdgcn_mfma_f32_16x16x32_bf16(
              qa[qi][ks], kb[kj][ks], sc[qi][kj], 0, 0, 0);

    // ---- fixed-max softmax: p = exp(s*0.1 - 12.8), per-lane only ----
    const bool dm = (kv0 == t0w);    // only the diagonal tile needs masking
    float p[2][2][4];
    #pragma unroll
    for (int qi = 0; qi < 2; ++qi) {
      #pragma unroll
      for (int r = 0; r < 4; ++r) {
        float p0 = __expf(fmaf(sc[qi][0][r], 0.1f, -12.8f));
        float p1 = __expf(fmaf(sc[qi][1][r], 0.1f, -12.8f));
        if (dm) {
          int row = t0w + qi*16 + hi*4 + r;
          p0 = (kv0 + lo      <= row) ? p0 : 0.f;
          p1 = (kv0 + 16 + lo <= row) ? p1 : 0.f;
        }
        lrow[qi][r] += p0 + p1;
        p[qi][0][r] = p0; p[qi][1][r] = p1;
      }
    }

    // ---- P transpose via wave-private swizzled LDS (in-order, no barrier) ----
    #pragma unroll
    for (int qi = 0; qi < 2; ++qi)
      #pragma unroll
      for (int kj = 0; kj < 2; ++kj)
        #pragma unroll
        for (int r = 0; r < 4; ++r) {
          int row = qi*16 + hi*4 + r;
          int col = kj*16 + lo;
          int ba = (row*64 + col*2) ^ ((row & 7) << 4);
          *(u16*)((char*)Pl + wv*2048 + ba) = f2b(p[qi][kj][r]);
        }
    short8 pa[2];
    #pragma unroll
    for (int qi = 0; qi < 2; ++qi) {
      int row = qi*16 + lo;
      int ba = (row*64 + hi*16) ^ ((row & 7) << 4);
      pa[qi] = *(const short8*)((char*)Pl + wv*2048 + ba);
    }
    // ---- PV (no rescale ever — fixed max) ----
    #pragma unroll
    for (int dj = 0; dj < 8; ++dj)
      #pragma unroll
      for (int qi = 0; qi < 2; ++qi)
        acc[qi][dj] = __builtin_amdgcn_mfma_f32_16x16x32_bf16(
            pa[qi], vb[dj], acc[qi][dj], 0, 0, 0);
  }

  // ---- per-wave l reduction across the 16 lo-lanes ----
  #pragma unroll
  for (int qi = 0; qi < 2; ++qi)
    #pragma unroll
    for (int r = 0; r < 4; ++r) {
      float lv = lrow[qi][r];
      lv += __shfl_xor(lv, 1);
      lv += __shfl_xor(lv, 2);
      lv += __shfl_xor(lv, 4);
      lv += __shfl_xor(lv, 8);
      lrow[qi][r] = lv;
    }

  // ---- waves 1-3: publish partials (packed bf16, conflict-free layout) ----
  if (wv > 0) {
    #pragma unroll
    for (int qi = 0; qi < 2; ++qi) {
      #pragma unroll
      for (int dj = 0; dj < 8; ++dj)
        #pragma unroll
        for (int rp = 0; rp < 2; ++rp) {
          u32 pk = (u32)f2b(acc[qi][dj][2*rp]) |
                   ((u32)f2b(acc[qi][dj][2*rp+1]) << 16);
          Pacc[wv-1][(qi*8 + dj)*2 + rp][lane] = pk;
        }
      #pragma unroll
      for (int r = 0; r < 4; ++r)
        if (lo == 0) Lacc[wv-1][(qi*4 + r)*4 + hi] = lrow[qi][r];
    }
  }
  __syncthreads();
  if (wv > 0) return;

  // ---- wave 0: sum partials, gate, write yb ----
  #pragma unroll
  for (int qi = 0; qi < 2; ++qi) {
    #pragma unroll
    for (int dj = 0; dj < 8; ++dj)
      #pragma unroll
      for (int rp = 0; rp < 2; ++rp) {
        #pragma unroll
        for (int w = 0; w < 3; ++w) {
          u32 pk = Pacc[w][(qi*8 + dj)*2 + rp][lane];
          acc[qi][dj][2*rp]   += b2f((u16)(pk & 0xffff));
          acc[qi][dj][2*rp+1] += b2f((u16)(pk >> 16));
        }
      }
    #pragma unroll
    for (int r = 0; r < 4; ++r)
      #pragma unroll
      for (int w = 0; w < 3; ++w)
        lrow[qi][r] += Lacc[w][(qi*4 + r)*4 + hi];
  }

  #pragma unroll
  for (int qi = 0; qi < 2; ++qi)
    #pragma unroll
    for (int r = 0; r < 4; ++r) {
      int trow = t0w + qi*16 + hi*4 + r;
      size_t bt = (size_t)b*T_ + trow;
      float dotg = 0.f;
      #pragma unroll
      for (int jj = 0; jj < 12; ++jj)
        dotg += x[bt*E_ + jj]*Wg[h*12 + jj];
      float g = 1.f/(1.f + __expf(-dotg));
      float coef = g / lrow[qi][r];
      #pragma unroll
      for (int dj = 0; dj < 8; ++dj)
        yb[bt*E_ + h*D_ + dj*16 + lo] = f2b(acc[qi][dj][r]*coef);
    }
}

// ---------------------------------------------------------------------------
extern "C" void kernel_launch(void* const* d_in, const int* in_sizes, int n_in,
                              void* d_out, int out_size, void* d_ws, size_t ws_size,
                              hipStream_t stream) {
  const float* x    = (const float*)d_in[0];
  const float* v1   = (const float*)d_in[1];
  const float* Wq   = (const float*)d_in[2];
  const float* Wk   = (const float*)d_in[3];
  const float* Wv   = (const float*)d_in[4];
  const float* lamb = (const float*)d_in[5];
  const float* Wo   = (const float*)d_in[6];
  const float* Wg   = (const float*)d_in[7];
  float* out = (float*)d_out;

  // workspace layout (u16 units for bf16 buffers)
  u16* xb   = (u16*)d_ws;
  u16* qkvb = xb   + (size_t)M_*E_;        // 8192*1024
  u16* qn   = qkvb + (size_t)M_*1024;
  u16* kn   = qn   + (size_t)M_*E_;
  u16* vn   = kn   + (size_t)M_*D_;
  u16* vnt  = vn   + (size_t)M_*D_;
  u16* yb   = vnt  + (size_t)M_*D_;
  u16* Wqb  = yb   + (size_t)M_*E_;
  u16* Wkb  = Wqb  + (size_t)E_*E_;
  u16* Wvb  = Wkb  + (size_t)D_*E_;
  u16* Wob  = Wvb  + (size_t)D_*E_;
  float* cosT = (float*)(Wob + (size_t)E_*E_);
  float* sinT = cosT + T_*64;

  k_rope_tables<<<T_, 64, 0, stream>>>(cosT, sinT);

  k_f2b<<<(M_*E_/4 + 255)/256, 256, 0, stream>>>(x,  xb,  M_*E_);
  k_f2b<<<(E_*E_/4 + 255)/256, 256, 0, stream>>>(Wq, Wqb, E_*E_);
  k_f2b<<<(D_*E_/4 + 255)/256, 256, 0, stream>>>(Wk, Wkb, D_*E_);
  k_f2b<<<(D_*E_/4 + 255)/256, 256, 0, stream>>>(Wv, Wvb, D_*E_);
  k_f2b<<<(E_*E_/4 + 255)/256, 256, 0, stream>>>(Wo, Wob, E_*E_);

  k_gemm_bf16<<<dim3(M_/128, 6), 256, 0, stream>>>(xb, Wqb, qkvb, 1024, 1, 0);
  k_gemm_bf16<<<dim3(M_/128, 1), 256, 0, stream>>>(xb, Wkb, qkvb, 1024, 1, 768);
  k_gemm_bf16<<<dim3(M_/128, 1), 256, 0, stream>>>(xb, Wvb, qkvb, 1024, 1, 896);

  k_vmix_norm_rope<<<dim3(M_, 8), 128, 0, stream>>>(qkvb, v1, lamb, cosT, sinT,
                                                    qn, kn, vn);
  k_transpose_v<<<dim3(T_/64, B_), 256, 0, stream>>>(vn, vnt);

  k_attn_mfma<<<B_*H_*(T_/32), 256, 0, stream>>>(qn, kn, vnt, x, Wg, yb);

  k_gemm_bf16<<<dim3(M_/128, 6), 256, 0, stream>>>(yb, Wob, out, 768, 0, 0);

  hipMemcpyAsync(out + (size_t)M_*E_, v1, (size_t)M_*D_*sizeof(float),
                 hipMemcpyDeviceToDevice, stream);
}

// Round 11
// 276.030 us; speedup vs baseline: 1.5165x; 1.1099x over previous
//
#include <hip/hip_runtime.h>
#include <hip/hip_bf16.h>
#include <math.h>

// Problem constants
#define B_ 4
#define T_ 2048
#define E_ 768
#define H_ 6
#define D_ 128
#define M_ (B_*T_)   // 8192 rows

typedef __attribute__((ext_vector_type(8))) short short8;
typedef __attribute__((ext_vector_type(4))) float f32x4;
typedef __attribute__((ext_vector_type(4))) unsigned int u32x4;
typedef unsigned short u16;
typedef unsigned int u32;

__device__ inline u16 f2b(float x) {
  union { float f; unsigned u; } c; c.f = x;
  unsigned r = (c.u + 0x7fff + ((c.u >> 16) & 1)) >> 16;  // RNE
  return (u16)r;
}
__device__ inline float b2f(u16 x) {
  union { unsigned u; float f; } c; c.u = ((unsigned)x) << 16;
  return c.f;
}
// round-half-up pack of two f32 into packed bf16 pair (lo = a, hi = b)
__device__ inline u32 pkbf(float a, float b) {
  union { float f; u32 u; } ca, cb; ca.f = a; cb.f = b;
  return ((ca.u + 0x8000u) >> 16) | ((cb.u + 0x8000u) & 0xffff0000u);
}

// ---------------------------------------------------------------------------
// K0: RoPE tables
// ---------------------------------------------------------------------------
__global__ void k_rope_tables(float* __restrict__ cosT, float* __restrict__ sinT) {
  int t = blockIdx.x;
  int j = threadIdx.x; // 0..63
  float inv = powf(10000.0f, -(float)j * (1.0f/64.0f));
  float f = (float)t * inv;
  cosT[t*64 + j] = cosf(f);
  sinT[t*64 + j] = sinf(f);
}

// ---------------------------------------------------------------------------
// K1: bf16 MFMA GEMM with fused f32->bf16 staging conversion.
// C[m][cb+n] = sum_k A[m][k]*W[wr0+n][k], K=768.
// A: f32 (ABF16=0) or bf16 (ABF16=1). W always f32, converted in staging.
// QKV fusion: blockIdx.y<nyq -> Wq col-block; ==nyq -> Wk; ==nyq+1 -> Wv.
// Tile 128x128, BK=64, 4 waves, LDS XOR-swizzled ((row&7)<<4).
// ---------------------------------------------------------------------------
template<int ABF16>
__global__ __launch_bounds__(256) void k_gemm(
    const void* __restrict__ Ap, const float* __restrict__ W0,
    const float* __restrict__ W1, const float* __restrict__ W2,
    int nyq, void* __restrict__ Cout, int ldc, int outBf16) {
  __shared__ __align__(16) u16 As[128*64];
  __shared__ __align__(16) u16 Bs[128*64];
  const int tid  = threadIdx.x;
  const int lane = tid & 63;
  const int wv   = tid >> 6;
  const int lo   = lane & 15;
  const int hi   = lane >> 4;
  const int wm   = wv >> 1;
  const int wn   = wv & 1;
  const int m0   = blockIdx.x * 128;
  const int by   = blockIdx.y;

  const float* W; int wr0, cb;
  if (by < nyq)       { W = W0; wr0 = by*128; cb = by*128; }
  else if (by == nyq) { W = W1; wr0 = 0;      cb = nyq*128; }
  else                { W = W2; wr0 = 0;      cb = nyq*128 + 128; }

  f32x4 acc[4][4];
  #pragma unroll
  for (int i = 0; i < 4; ++i)
    #pragma unroll
    for (int j = 0; j < 4; ++j) {
      acc[i][j][0]=0.f; acc[i][j][1]=0.f; acc[i][j][2]=0.f; acc[i][j][3]=0.f;
    }

  for (int k0 = 0; k0 < E_; k0 += 64) {
    __syncthreads();
    #pragma unroll
    for (int i = 0; i < 4; ++i) {
      int s   = i*256 + tid;     // 0..1023
      int row = s >> 3;          // 0..127
      int sl  = s & 7;           // 16B slot in 128B row
      int ba  = (row*128 + sl*16) ^ ((row & 7) << 4);
      // A slot
      if (ABF16) {
        short8 va = *reinterpret_cast<const short8*>(
            (const u16*)Ap + (size_t)(m0+row)*E_ + k0 + sl*8);
        *(short8*)((char*)As + ba) = va;
      } else {
        const float* af = (const float*)Ap + (size_t)(m0+row)*E_ + k0 + sl*8;
        float4 f0 = *reinterpret_cast<const float4*>(af);
        float4 f1 = *reinterpret_cast<const float4*>(af + 4);
        u32x4 pk;
        pk[0]=pkbf(f0.x,f0.y); pk[1]=pkbf(f0.z,f0.w);
        pk[2]=pkbf(f1.x,f1.y); pk[3]=pkbf(f1.z,f1.w);
        *(u32x4*)((char*)As + ba) = pk;
      }
      // W slot (always f32)
      {
        const float* wf = W + (size_t)(wr0+row)*E_ + k0 + sl*8;
        float4 f0 = *reinterpret_cast<const float4*>(wf);
        float4 f1 = *reinterpret_cast<const float4*>(wf + 4);
        u32x4 pk;
        pk[0]=pkbf(f0.x,f0.y); pk[1]=pkbf(f0.z,f0.w);
        pk[2]=pkbf(f1.x,f1.y); pk[3]=pkbf(f1.z,f1.w);
        *(u32x4*)((char*)Bs + ba) = pk;
      }
    }
    __syncthreads();
    #pragma unroll
    for (int ks = 0; ks < 2; ++ks) {
      short8 af[4], bf[4];
      #pragma unroll
      for (int mi = 0; mi < 4; ++mi) {
        int row = wm*64 + mi*16 + lo;
        int ba = (row*128 + ks*64 + hi*16) ^ ((row & 7) << 4);
        af[mi] = *(const short8*)((char*)As + ba);
      }
      #pragma unroll
      for (int nf = 0; nf < 4; ++nf) {
        int row = wn*64 + nf*16 + lo;
        int ba = (row*128 + ks*64 + hi*16) ^ ((row & 7) << 4);
        bf[nf] = *(const short8*)((char*)Bs + ba);
      }
      #pragma unroll
      for (int mi = 0; mi < 4; ++mi)
        #pragma unroll
        for (int nf = 0; nf < 4; ++nf)
          acc[mi][nf] = __builtin_amdgcn_mfma_f32_16x16x32_bf16(
              af[mi], bf[nf], acc[mi][nf], 0, 0, 0);
    }
  }

  #pragma unroll
  for (int mi = 0; mi < 4; ++mi)
    #pragma unroll
    for (int nf = 0; nf < 4; ++nf)
      #pragma unroll
      for (int r = 0; r < 4; ++r) {
        int m = m0 + wm*64 + mi*16 + hi*4 + r;
        int n = cb + wn*64 + nf*16 + lo;
        float v = acc[mi][nf][r];
        if (outBf16) ((u16*)Cout)[(size_t)m*ldc + n] = f2b(v);
        else         ((float*)Cout)[(size_t)m*ldc + n] = v;
      }
}

// ---------------------------------------------------------------------------
// K2: v-mix + rms-norm + rope (reads bf16 qkv). Outputs bf16 qn/kn/vn.
// ---------------------------------------------------------------------------
__global__ __launch_bounds__(128) void k_vmix_norm_rope(
    const u16* __restrict__ qkv, const float* __restrict__ v1,
    const float* __restrict__ lambp,
    const float* __restrict__ cosT, const float* __restrict__ sinT,
    u16* __restrict__ qn, u16* __restrict__ kn, u16* __restrict__ vn) {
  const int bt  = blockIdx.x;
  const int row = blockIdx.y;          // 0..5 q heads, 6 = k, 7 = v
  const int d   = threadIdx.x;
  const int t   = bt & (T_-1);
  const int b   = bt >> 11;
  float val = b2f(qkv[(size_t)bt*1024 + row*128 + d]);
  if (row == 7) {
    float lamb = *lambp;
    float mix = (1.0f - lamb)*val + lamb*v1[(size_t)bt*128 + d];
    vn[(size_t)bt*128 + d] = f2b(mix);
    return;
  }
  __shared__ float red[2];
  __shared__ float nbuf[128];
  float ss = val*val;
  #pragma unroll
  for (int off = 32; off > 0; off >>= 1) ss += __shfl_xor(ss, off);
  if ((threadIdx.x & 63) == 0) red[threadIdx.x >> 6] = ss;
  __syncthreads();
  float sum = red[0] + red[1];
  float r = rsqrtf(sum * (1.0f/128.0f) + 1e-6f);
  nbuf[d] = val * r;
  __syncthreads();
  int j = d & 63;
  float c = cosT[t*64 + j];
  float s = sinT[t*64 + j];
  float o = (d < 64) ? (nbuf[d]*c + nbuf[d+64]*s)
                     : (-nbuf[d-64]*s + nbuf[d]*c);
  if (row < 6) qn[((size_t)(b*H_ + row)*T_ + t)*D_ + d] = f2b(o);
  else         kn[(size_t)bt*D_ + d] = f2b(o);
}

// ---------------------------------------------------------------------------
// K2b: vn [b][t][d] -> vnt [b][d][t]  (LDS-tiled transpose, 64t x 128d tiles)
// ---------------------------------------------------------------------------
__global__ __launch_bounds__(256) void k_transpose_v(
    const u16* __restrict__ vn, u16* __restrict__ vnt) {
  __shared__ u16 tile[64][136];
  const int tid = threadIdx.x;
  const int b  = blockIdx.y;
  const int t0 = blockIdx.x * 64;
  {
    int tr = tid >> 2;           // 0..63
    int dc = (tid & 3) * 32;
    const u16* src = vn + ((size_t)(b*T_ + t0 + tr))*D_ + dc;
    #pragma unroll
    for (int j = 0; j < 4; ++j) {
      short8 v = *reinterpret_cast<const short8*>(src + j*8);
      *reinterpret_cast<short8*>(&tile[tr][dc + j*8]) = v;
    }
  }
  __syncthreads();
  {
    int dr = tid >> 1;           // 0..127
    int tc = (tid & 1) * 32;
    #pragma unroll
    for (int j = 0; j < 4; ++j) {
      short8 o;
      #pragma unroll
      for (int jj = 0; jj < 8; ++jj) o[jj] = (short)tile[tc + j*8 + jj][dr];
      *reinterpret_cast<short8*>(
          vnt + ((size_t)(b*D_ + dr))*T_ + t0 + tc + j*8) = o;
    }
  }
}

// ---------------------------------------------------------------------------
// K3: MFMA flash attention (MQA), fixed-max softmax, intra-block split-S,
// K-PREFETCH software pipeline (next iteration's K frags load under current
// tile's compute; V latency hides under QK+softmax).
// Block = 4 waves sharing ONE 32-row q-tile; wave w handles KV tiles
// w, w+4, w+8, ...; partials combine by summation (fixed max).
// ---------------------------------------------------------------------------
#define KVB 32
__global__ __launch_bounds__(256) void k_attn_mfma(
    const u16* __restrict__ qn, const u16* __restrict__ kn,
    const u16* __restrict__ vnt, const float* __restrict__ x,
    const float* __restrict__ Wg, u16* __restrict__ yb) {
  __shared__ __align__(16) u16 Pl[4*1024];       // per-wave P transpose, 8KB
  __shared__ u32   Pacc[3][32][64];              // packed bf16 partials, 24KB
  __shared__ float Lacc[3][32];                  // l partials

  const int tid  = threadIdx.x;
  const int lane = tid & 63;
  const int wv   = tid >> 6;
  const int lo   = lane & 15;
  const int hi   = lane >> 4;

  const int bid  = blockIdx.x;
  const int rank = bid / 24;           // 0..63, 0 = biggest tile
  const int bh   = bid % 24;
  const int h    = bh % H_;
  const int b    = bh / H_;
  const int t0w  = (63 - rank) * 32;

  short8 qa[2][4];
  const u16* qb = qn + ((size_t)(b*H_ + h)*T_ + t0w)*D_;
  #pragma unroll
  for (int qi = 0; qi < 2; ++qi)
    #pragma unroll
    for (int ks = 0; ks < 4; ++ks)
      qa[qi][ks] = *(const short8*)(qb + (size_t)(qi*16 + lo)*D_ + ks*32 + hi*8);

  f32x4 acc[2][8];
  float lrow[2][4];
  #pragma unroll
  for (int qi = 0; qi < 2; ++qi) {
    #pragma unroll
    for (int dj = 0; dj < 8; ++dj) {
      acc[qi][dj][0]=0.f; acc[qi][dj][1]=0.f; acc[qi][dj][2]=0.f; acc[qi][dj][3]=0.f;
    }
    #pragma unroll
    for (int r = 0; r < 4; ++r) lrow[qi][r] = 0.f;
  }

  const u16* kg  = kn  + (size_t)b*T_*D_;
  const u16* vgt = vnt + (size_t)b*D_*T_;

  int kv0 = wv*KVB;
  if (kv0 <= t0w) {
    // prologue: load first K tile
    short8 kb[2][4];
    #pragma unroll
    for (int kj = 0; kj < 2; ++kj)
      #pragma unroll
      for (int ks = 0; ks < 4; ++ks)
        kb[kj][ks] = *(const short8*)(
            kg + (size_t)(kv0 + kj*16 + lo)*D_ + ks*32 + hi*8);

    #pragma unroll 2
    for (; kv0 <= t0w; kv0 += 4*KVB) {
      const int kvn = kv0 + 4*KVB;
      const bool more = (kvn <= t0w);     // wave-uniform
      // ---- prefetch next K tile (hidden under this tile's compute) ----
      short8 kbn[2][4];
      if (more) {
        #pragma unroll
        for (int kj = 0; kj < 2; ++kj)
          #pragma unroll
          for (int ks = 0; ks < 4; ++ks)
            kbn[kj][ks] = *(const short8*)(
                kg + (size_t)(kvn + kj*16 + lo)*D_ + ks*32 + hi*8);
      }
      // ---- V fragments for current tile (latency hides under QK) ----
      short8 vb[8];
      #pragma unroll
      for (int dj = 0; dj < 8; ++dj)
        vb[dj] = *(const short8*)(
            vgt + (size_t)(dj*16 + lo)*T_ + kv0 + hi*8);

      // ---- QK^T ----
      f32x4 sc[2][2];
      #pragma unroll
      for (int qi = 0; qi < 2; ++qi)
        #pragma unroll
        for (int kj = 0; kj < 2; ++kj) {
          sc[qi][kj][0]=0.f; sc[qi][kj][1]=0.f; sc[qi][kj][2]=0.f; sc[qi][kj][3]=0.f;
        }
      #pragma unroll
      for (int kj = 0; kj < 2; ++kj)
        #pragma unroll
        for (int qi = 0; qi < 2; ++qi)
          #pragma unroll
          for (int ks = 0; ks < 4; ++ks)
            sc[qi][kj] = __builtin_amdgcn_mfma_f32_16x16x32_bf16(
                qa[qi][ks], kb[kj][ks], sc[qi][kj], 0, 0, 0);

      // ---- fixed-max softmax: p = exp(s*0.1 - 12.8), per-lane only ----
      const bool dm = (kv0 == t0w);
      float p[2][2][4];
      #pragma unroll
      for (int qi = 0; qi < 2; ++qi) {
        #pragma unroll
        for (int r = 0; r < 4; ++r) {
          float p0 = __expf(fmaf(sc[qi][0][r], 0.1f, -12.8f));
          float p1 = __expf(fmaf(sc[qi][1][r], 0.1f, -12.8f));
          if (dm) {
            int row = t0w + qi*16 + hi*4 + r;
            p0 = (kv0 + lo      <= row) ? p0 : 0.f;
            p1 = (kv0 + 16 + lo <= row) ? p1 : 0.f;
          }
          lrow[qi][r] += p0 + p1;
          p[qi][0][r] = p0; p[qi][1][r] = p1;
        }
      }

      // ---- P transpose via wave-private swizzled LDS ----
      #pragma unroll
      for (int qi = 0; qi < 2; ++qi)
        #pragma unroll
        for (int kj = 0; kj < 2; ++kj)
          #pragma unroll
          for (int r = 0; r < 4; ++r) {
            int row = qi*16 + hi*4 + r;
            int col = kj*16 + lo;
            int ba = (row*64 + col*2) ^ ((row & 7) << 4);
            *(u16*)((char*)Pl + wv*2048 + ba) = f2b(p[qi][kj][r]);
          }
      short8 pa[2];
      #pragma unroll
      for (int qi = 0; qi < 2; ++qi) {
        int row = qi*16 + lo;
        int ba = (row*64 + hi*16) ^ ((row & 7) << 4);
        pa[qi] = *(const short8*)((char*)Pl + wv*2048 + ba);
      }
      // ---- PV ----
      #pragma unroll
      for (int dj = 0; dj < 8; ++dj)
        #pragma unroll
        for (int qi = 0; qi < 2; ++qi)
          acc[qi][dj] = __builtin_amdgcn_mfma_f32_16x16x32_bf16(
              pa[qi], vb[dj], acc[qi][dj], 0, 0, 0);

      // ---- rotate prefetched K into place ----
      if (more) {
        #pragma unroll
        for (int kj = 0; kj < 2; ++kj)
          #pragma unroll
          for (int ks = 0; ks < 4; ++ks)
            kb[kj][ks] = kbn[kj][ks];
      }
    }
  }

  // ---- per-wave l reduction across the 16 lo-lanes ----
  #pragma unroll
  for (int qi = 0; qi < 2; ++qi)
    #pragma unroll
    for (int r = 0; r < 4; ++r) {
      float lv = lrow[qi][r];
      lv += __shfl_xor(lv, 1);
      lv += __shfl_xor(lv, 2);
      lv += __shfl_xor(lv, 4);
      lv += __shfl_xor(lv, 8);
      lrow[qi][r] = lv;
    }

  // ---- waves 1-3: publish partials ----
  if (wv > 0) {
    #pragma unroll
    for (int qi = 0; qi < 2; ++qi) {
      #pragma unroll
      for (int dj = 0; dj < 8; ++dj)
        #pragma unroll
        for (int rp = 0; rp < 2; ++rp) {
          u32 pk = (u32)f2b(acc[qi][dj][2*rp]) |
                   ((u32)f2b(acc[qi][dj][2*rp+1]) << 16);
          Pacc[wv-1][(qi*8 + dj)*2 + rp][lane] = pk;
        }
      #pragma unroll
      for (int r = 0; r < 4; ++r)
        if (lo == 0) Lacc[wv-1][(qi*4 + r)*4 + hi] = lrow[qi][r];
    }
  }
  __syncthreads();
  if (wv > 0) return;

  // ---- wave 0: sum partials, gate, write yb ----
  #pragma unroll
  for (int qi = 0; qi < 2; ++qi) {
    #pragma unroll
    for (int dj = 0; dj < 8; ++dj)
      #pragma unroll
      for (int rp = 0; rp < 2; ++rp) {
        #pragma unroll
        for (int w = 0; w < 3; ++w) {
          u32 pk = Pacc[w][(qi*8 + dj)*2 + rp][lane];
          acc[qi][dj][2*rp]   += b2f((u16)(pk & 0xffff));
          acc[qi][dj][2*rp+1] += b2f((u16)(pk >> 16));
        }
      }
    #pragma unroll
    for (int r = 0; r < 4; ++r)
      #pragma unroll
      for (int w = 0; w < 3; ++w)
        lrow[qi][r] += Lacc[w][(qi*4 + r)*4 + hi];
  }

  #pragma unroll
  for (int qi = 0; qi < 2; ++qi)
    #pragma unroll
    for (int r = 0; r < 4; ++r) {
      int trow = t0w + qi*16 + hi*4 + r;
      size_t bt = (size_t)b*T_ + trow;
      float dotg = 0.f;
      #pragma unroll
      for (int jj = 0; jj < 12; ++jj)
        dotg += x[bt*E_ + jj]*Wg[h*12 + jj];
      float g = 1.f/(1.f + __expf(-dotg));
      float coef = g / lrow[qi][r];
      #pragma unroll
      for (int dj = 0; dj < 8; ++dj)
        yb[bt*E_ + h*D_ + dj*16 + lo] = f2b(acc[qi][dj][r]*coef);
    }
}

// ---------------------------------------------------------------------------
extern "C" void kernel_launch(void* const* d_in, const int* in_sizes, int n_in,
                              void* d_out, int out_size, void* d_ws, size_t ws_size,
                              hipStream_t stream) {
  const float* x    = (const float*)d_in[0];
  const float* v1   = (const float*)d_in[1];
  const float* Wq   = (const float*)d_in[2];
  const float* Wk   = (const float*)d_in[3];
  const float* Wv   = (const float*)d_in[4];
  const float* lamb = (const float*)d_in[5];
  const float* Wo   = (const float*)d_in[6];
  const float* Wg   = (const float*)d_in[7];
  float* out = (float*)d_out;

  // workspace layout (u16 units for bf16 buffers)
  u16* qkvb = (u16*)d_ws;                  // 8192*1024
  u16* qn   = qkvb + (size_t)M_*1024;
  u16* kn   = qn   + (size_t)M_*E_;
  u16* vn   = kn   + (size_t)M_*D_;
  u16* vnt  = vn   + (size_t)M_*D_;
  u16* yb   = vnt  + (size_t)M_*D_;
  float* cosT = (float*)(yb + (size_t)M_*E_);
  float* sinT = cosT + T_*64;

  k_rope_tables<<<T_, 64, 0, stream>>>(cosT, sinT);

  // fused QKV projection: y-blocks 0..5 = Wq, 6 = Wk, 7 = Wv
  k_gemm<0><<<dim3(M_/128, 8), 256, 0, stream>>>(
      x, Wq, Wk, Wv, 6, qkvb, 1024, 1);

  k_vmix_norm_rope<<<dim3(M_, 8), 128, 0, stream>>>(qkvb, v1, lamb, cosT, sinT,
                                                    qn, kn, vn);
  k_transpose_v<<<dim3(T_/64, B_), 256, 0, stream>>>(vn, vnt);

  k_attn_mfma<<<B_*H_*(T_/32), 256, 0, stream>>>(qn, kn, vnt, x, Wg, yb);

  k_gemm<1><<<dim3(M_/128, 6), 256, 0, stream>>>(
      yb, Wo, Wo, Wo, 6, out, 768, 0);

  hipMemcpyAsync(out + (size_t)M_*E_, v1, (size_t)M_*D_*sizeof(float),
                 hipMemcpyDeviceToDevice, stream);
}

// Round 12
// 226.417 us; speedup vs baseline: 1.8489x; 1.2191x over previous
//
#include <hip/hip_runtime.h>
#include <hip/hip_bf16.h>
#include <math.h>

// Problem constants
#define B_ 4
#define T_ 2048
#define E_ 768
#define H_ 6
#define D_ 128
#define M_ (B_*T_)   // 8192 rows

typedef __attribute__((ext_vector_type(8))) short short8;
typedef __attribute__((ext_vector_type(4))) float f32x4;
typedef __attribute__((ext_vector_type(4))) unsigned int u32x4;
typedef unsigned short u16;
typedef unsigned int u32;

__device__ inline u16 f2b(float x) {
  union { float f; unsigned u; } c; c.f = x;
  unsigned r = (c.u + 0x7fff + ((c.u >> 16) & 1)) >> 16;  // RNE
  return (u16)r;
}
__device__ inline float b2f(u16 x) {
  union { unsigned u; float f; } c; c.u = ((unsigned)x) << 16;
  return c.f;
}
// round-half-up pack of two f32 into packed bf16 pair (lo = a, hi = b)
__device__ inline u32 pkbf(float a, float b) {
  union { float f; u32 u; } ca, cb; ca.f = a; cb.f = b;
  return ((ca.u + 0x8000u) >> 16) | ((cb.u + 0x8000u) & 0xffff0000u);
}

// ---------------------------------------------------------------------------
// K0: RoPE tables
// ---------------------------------------------------------------------------
__global__ void k_rope_tables(float* __restrict__ cosT, float* __restrict__ sinT) {
  int t = blockIdx.x;
  int j = threadIdx.x; // 0..63
  float inv = powf(10000.0f, -(float)j * (1.0f/64.0f));
  float f = (float)t * inv;
  cosT[t*64 + j] = cosf(f);
  sinT[t*64 + j] = sinf(f);
}

// ---------------------------------------------------------------------------
// K1: bf16 MFMA GEMM with fused f32->bf16 staging conversion.
// C[m][cb+n] = sum_k A[m][k]*W[wr0+n][k], K=768.
// A: f32 (ABF16=0) or bf16 (ABF16=1). W always f32, converted in staging.
// QKV fusion: blockIdx.y<nyq -> Wq col-block; ==nyq -> Wk; ==nyq+1 -> Wv.
// ---------------------------------------------------------------------------
template<int ABF16>
__global__ __launch_bounds__(256) void k_gemm(
    const void* __restrict__ Ap, const float* __restrict__ W0,
    const float* __restrict__ W1, const float* __restrict__ W2,
    int nyq, void* __restrict__ Cout, int ldc, int outBf16) {
  __shared__ __align__(16) u16 As[128*64];
  __shared__ __align__(16) u16 Bs[128*64];
  const int tid  = threadIdx.x;
  const int lane = tid & 63;
  const int wv   = tid >> 6;
  const int lo   = lane & 15;
  const int hi   = lane >> 4;
  const int wm   = wv >> 1;
  const int wn   = wv & 1;
  const int m0   = blockIdx.x * 128;
  const int by   = blockIdx.y;

  const float* W; int wr0, cb;
  if (by < nyq)       { W = W0; wr0 = by*128; cb = by*128; }
  else if (by == nyq) { W = W1; wr0 = 0;      cb = nyq*128; }
  else                { W = W2; wr0 = 0;      cb = nyq*128 + 128; }

  f32x4 acc[4][4];
  #pragma unroll
  for (int i = 0; i < 4; ++i)
    #pragma unroll
    for (int j = 0; j < 4; ++j) {
      acc[i][j][0]=0.f; acc[i][j][1]=0.f; acc[i][j][2]=0.f; acc[i][j][3]=0.f;
    }

  for (int k0 = 0; k0 < E_; k0 += 64) {
    __syncthreads();
    #pragma unroll
    for (int i = 0; i < 4; ++i) {
      int s   = i*256 + tid;     // 0..1023
      int row = s >> 3;          // 0..127
      int sl  = s & 7;           // 16B slot in 128B row
      int ba  = (row*128 + sl*16) ^ ((row & 7) << 4);
      if (ABF16) {
        short8 va = *reinterpret_cast<const short8*>(
            (const u16*)Ap + (size_t)(m0+row)*E_ + k0 + sl*8);
        *(short8*)((char*)As + ba) = va;
      } else {
        const float* af = (const float*)Ap + (size_t)(m0+row)*E_ + k0 + sl*8;
        float4 f0 = *reinterpret_cast<const float4*>(af);
        float4 f1 = *reinterpret_cast<const float4*>(af + 4);
        u32x4 pk;
        pk[0]=pkbf(f0.x,f0.y); pk[1]=pkbf(f0.z,f0.w);
        pk[2]=pkbf(f1.x,f1.y); pk[3]=pkbf(f1.z,f1.w);
        *(u32x4*)((char*)As + ba) = pk;
      }
      {
        const float* wf = W + (size_t)(wr0+row)*E_ + k0 + sl*8;
        float4 f0 = *reinterpret_cast<const float4*>(wf);
        float4 f1 = *reinterpret_cast<const float4*>(wf + 4);
        u32x4 pk;
        pk[0]=pkbf(f0.x,f0.y); pk[1]=pkbf(f0.z,f0.w);
        pk[2]=pkbf(f1.x,f1.y); pk[3]=pkbf(f1.z,f1.w);
        *(u32x4*)((char*)Bs + ba) = pk;
      }
    }
    __syncthreads();
    #pragma unroll
    for (int ks = 0; ks < 2; ++ks) {
      short8 af[4], bf[4];
      #pragma unroll
      for (int mi = 0; mi < 4; ++mi) {
        int row = wm*64 + mi*16 + lo;
        int ba = (row*128 + ks*64 + hi*16) ^ ((row & 7) << 4);
        af[mi] = *(const short8*)((char*)As + ba);
      }
      #pragma unroll
      for (int nf = 0; nf < 4; ++nf) {
        int row = wn*64 + nf*16 + lo;
        int ba = (row*128 + ks*64 + hi*16) ^ ((row & 7) << 4);
        bf[nf] = *(const short8*)((char*)Bs + ba);
      }
      #pragma unroll
      for (int mi = 0; mi < 4; ++mi)
        #pragma unroll
        for (int nf = 0; nf < 4; ++nf)
          acc[mi][nf] = __builtin_amdgcn_mfma_f32_16x16x32_bf16(
              af[mi], bf[nf], acc[mi][nf], 0, 0, 0);
    }
  }

  #pragma unroll
  for (int mi = 0; mi < 4; ++mi)
    #pragma unroll
    for (int nf = 0; nf < 4; ++nf)
      #pragma unroll
      for (int r = 0; r < 4; ++r) {
        int m = m0 + wm*64 + mi*16 + hi*4 + r;
        int n = cb + wn*64 + nf*16 + lo;
        float v = acc[mi][nf][r];
        if (outBf16) ((u16*)Cout)[(size_t)m*ldc + n] = f2b(v);
        else         ((float*)Cout)[(size_t)m*ldc + n] = v;
      }
}

// ---------------------------------------------------------------------------
// K2: v-mix + rms-norm + rope (reads bf16 qkv). Outputs bf16 qn/kn/vn.
// ---------------------------------------------------------------------------
__global__ __launch_bounds__(128) void k_vmix_norm_rope(
    const u16* __restrict__ qkv, const float* __restrict__ v1,
    const float* __restrict__ lambp,
    const float* __restrict__ cosT, const float* __restrict__ sinT,
    u16* __restrict__ qn, u16* __restrict__ kn, u16* __restrict__ vn) {
  const int bt  = blockIdx.x;
  const int row = blockIdx.y;          // 0..5 q heads, 6 = k, 7 = v
  const int d   = threadIdx.x;
  const int t   = bt & (T_-1);
  const int b   = bt >> 11;
  float val = b2f(qkv[(size_t)bt*1024 + row*128 + d]);
  if (row == 7) {
    float lamb = *lambp;
    float mix = (1.0f - lamb)*val + lamb*v1[(size_t)bt*128 + d];
    vn[(size_t)bt*128 + d] = f2b(mix);
    return;
  }
  __shared__ float red[2];
  __shared__ float nbuf[128];
  float ss = val*val;
  #pragma unroll
  for (int off = 32; off > 0; off >>= 1) ss += __shfl_xor(ss, off);
  if ((threadIdx.x & 63) == 0) red[threadIdx.x >> 6] = ss;
  __syncthreads();
  float sum = red[0] + red[1];
  float r = rsqrtf(sum * (1.0f/128.0f) + 1e-6f);
  nbuf[d] = val * r;
  __syncthreads();
  int j = d & 63;
  float c = cosT[t*64 + j];
  float s = sinT[t*64 + j];
  float o = (d < 64) ? (nbuf[d]*c + nbuf[d+64]*s)
                     : (-nbuf[d-64]*s + nbuf[d]*c);
  if (row < 6) qn[((size_t)(b*H_ + row)*T_ + t)*D_ + d] = f2b(o);
  else         kn[(size_t)bt*D_ + d] = f2b(o);
}

// ---------------------------------------------------------------------------
// K2b: pack K and V into MFMA fragment-major layout (coalesced attn loads).
// kf: [b][kt=t/16][ks=0..3][lane=0..63][8]   elem j = K[b][kt*16+(l&15)][ks*32+(l>>4)*8+j]
// vf: [b][vt=t/32][dj=0..7][lane=0..63][8]   elem j = V[b][vt*32+(l>>4)*8+j][dj*16+(l&15)]
// Grid (T/32, B), block 256. LDS-staged, coalesced global reads.
// ---------------------------------------------------------------------------
__global__ __launch_bounds__(256) void k_pack_frags(
    const u16* __restrict__ kn, const u16* __restrict__ vn,
    u16* __restrict__ kf, u16* __restrict__ vf) {
  __shared__ u16 Lk[32][136];
  __shared__ u16 Lv[32][136];
  const int tid = threadIdx.x;
  const int g = blockIdx.x;            // 32-row group, 0..63
  const int b = blockIdx.y;
  const int t0 = g*32;
  {
    int r = tid >> 3, c = (tid & 7)*16;
    const u16* ksrc = kn + ((size_t)(b*T_) + t0 + r)*D_ + c;
    const u16* vsrc = vn + ((size_t)(b*T_) + t0 + r)*D_ + c;
    *(short8*)&Lk[r][c]   = *(const short8*)ksrc;
    *(short8*)&Lk[r][c+8] = *(const short8*)(ksrc+8);
    *(short8*)&Lv[r][c]   = *(const short8*)vsrc;
    *(short8*)&Lv[r][c+8] = *(const short8*)(vsrc+8);
  }
  __syncthreads();
  const int lane = tid & 63, wv = tid >> 6;
  const int lo = lane & 15, hi = lane >> 4;
  // K chunks: wave w -> (kt=w>>1, ks=(w&1)) and (kt=w>>1, ks=(w&1)+2)
  #pragma unroll
  for (int it = 0; it < 2; ++it) {
    int kt = wv >> 1;
    int ks = (wv & 1) + it*2;
    short8 v = *(const short8*)&Lk[kt*16 + lo][ks*32 + hi*8];
    size_t base = ((((size_t)b*128) + g*2 + kt)*4 + ks)*512;
    *(short8*)(kf + base + lane*8) = v;
  }
  // V chunks: wave w -> dj = w and w+4
  #pragma unroll
  for (int it = 0; it < 2; ++it) {
    int dj = wv + it*4;
    short8 o;
    #pragma unroll
    for (int j = 0; j < 8; ++j) o[j] = (short)Lv[hi*8 + j][dj*16 + lo];
    size_t base = (((size_t)b*64 + g)*8 + dj)*512;
    *(short8*)(vf + base + lane*8) = o;
  }
}

// ---------------------------------------------------------------------------
// K3: MFMA flash attention (MQA), fixed-max softmax, intra-block split-S,
// K-prefetch pipeline, FRAGMENT-MAJOR coalesced K/V loads (base + lane*16B).
// ---------------------------------------------------------------------------
#define KVB 32
__global__ __launch_bounds__(256) void k_attn_mfma(
    const u16* __restrict__ qn, const u16* __restrict__ kf,
    const u16* __restrict__ vf, const float* __restrict__ x,
    const float* __restrict__ Wg, u16* __restrict__ yb) {
  __shared__ __align__(16) u16 Pl[4*1024];       // per-wave P transpose, 8KB
  __shared__ u32   Pacc[3][32][64];              // packed bf16 partials, 24KB
  __shared__ float Lacc[3][32];                  // l partials

  const int tid  = threadIdx.x;
  const int lane = tid & 63;
  const int wv   = tid >> 6;
  const int lo   = lane & 15;
  const int hi   = lane >> 4;

  const int bid  = blockIdx.x;
  const int rank = bid / 24;           // 0..63, 0 = biggest tile
  const int bh   = bid % 24;
  const int h    = bh % H_;
  const int b    = bh / H_;
  const int t0w  = (63 - rank) * 32;

  short8 qa[2][4];
  const u16* qb = qn + ((size_t)(b*H_ + h)*T_ + t0w)*D_;
  #pragma unroll
  for (int qi = 0; qi < 2; ++qi)
    #pragma unroll
    for (int ks = 0; ks < 4; ++ks)
      qa[qi][ks] = *(const short8*)(qb + (size_t)(qi*16 + lo)*D_ + ks*32 + hi*8);

  f32x4 acc[2][8];
  float lrow[2][4];
  #pragma unroll
  for (int qi = 0; qi < 2; ++qi) {
    #pragma unroll
    for (int dj = 0; dj < 8; ++dj) {
      acc[qi][dj][0]=0.f; acc[qi][dj][1]=0.f; acc[qi][dj][2]=0.f; acc[qi][dj][3]=0.f;
    }
    #pragma unroll
    for (int r = 0; r < 4; ++r) lrow[qi][r] = 0.f;
  }

  const u16* kfb = kf + (size_t)b*128*4*512;
  const u16* vfb = vf + (size_t)b*64*8*512;

  int kv0 = wv*KVB;
  if (kv0 <= t0w) {
    // prologue: load first K tile (coalesced fragment chunks)
    short8 kb[2][4];
    #pragma unroll
    for (int kj = 0; kj < 2; ++kj)
      #pragma unroll
      for (int ks = 0; ks < 4; ++ks)
        kb[kj][ks] = *(const short8*)(
            kfb + (size_t)(((kv0>>4) + kj)*4 + ks)*512 + lane*8);

    #pragma unroll 2
    for (; kv0 <= t0w; kv0 += 4*KVB) {
      const int kvn = kv0 + 4*KVB;
      const bool more = (kvn <= t0w);     // wave-uniform
      short8 kbn[2][4];
      if (more) {
        #pragma unroll
        for (int kj = 0; kj < 2; ++kj)
          #pragma unroll
          for (int ks = 0; ks < 4; ++ks)
            kbn[kj][ks] = *(const short8*)(
                kfb + (size_t)(((kvn>>4) + kj)*4 + ks)*512 + lane*8);
      }
      short8 vb[8];
      #pragma unroll
      for (int dj = 0; dj < 8; ++dj)
        vb[dj] = *(const short8*)(
            vfb + (size_t)((kv0>>5)*8 + dj)*512 + lane*8);

      // ---- QK^T ----
      f32x4 sc[2][2];
      #pragma unroll
      for (int qi = 0; qi < 2; ++qi)
        #pragma unroll
        for (int kj = 0; kj < 2; ++kj) {
          sc[qi][kj][0]=0.f; sc[qi][kj][1]=0.f; sc[qi][kj][2]=0.f; sc[qi][kj][3]=0.f;
        }
      #pragma unroll
      for (int kj = 0; kj < 2; ++kj)
        #pragma unroll
        for (int qi = 0; qi < 2; ++qi)
          #pragma unroll
          for (int ks = 0; ks < 4; ++ks)
            sc[qi][kj] = __builtin_amdgcn_mfma_f32_16x16x32_bf16(
                qa[qi][ks], kb[kj][ks], sc[qi][kj], 0, 0, 0);

      // ---- fixed-max softmax: p = exp(s*0.1 - 12.8), per-lane only ----
      const bool dm = (kv0 == t0w);
      float p[2][2][4];
      #pragma unroll
      for (int qi = 0; qi < 2; ++qi) {
        #pragma unroll
        for (int r = 0; r < 4; ++r) {
          float p0 = __expf(fmaf(sc[qi][0][r], 0.1f, -12.8f));
          float p1 = __expf(fmaf(sc[qi][1][r], 0.1f, -12.8f));
          if (dm) {
            int row = t0w + qi*16 + hi*4 + r;
            p0 = (kv0 + lo      <= row) ? p0 : 0.f;
            p1 = (kv0 + 16 + lo <= row) ? p1 : 0.f;
          }
          lrow[qi][r] += p0 + p1;
          p[qi][0][r] = p0; p[qi][1][r] = p1;
        }
      }

      // ---- P transpose via wave-private swizzled LDS ----
      #pragma unroll
      for (int qi = 0; qi < 2; ++qi)
        #pragma unroll
        for (int kj = 0; kj < 2; ++kj)
          #pragma unroll
          for (int r = 0; r < 4; ++r) {
            int row = qi*16 + hi*4 + r;
            int col = kj*16 + lo;
            int ba = (row*64 + col*2) ^ ((row & 7) << 4);
            *(u16*)((char*)Pl + wv*2048 + ba) = f2b(p[qi][kj][r]);
          }
      short8 pa[2];
      #pragma unroll
      for (int qi = 0; qi < 2; ++qi) {
        int row = qi*16 + lo;
        int ba = (row*64 + hi*16) ^ ((row & 7) << 4);
        pa[qi] = *(const short8*)((char*)Pl + wv*2048 + ba);
      }
      // ---- PV ----
      #pragma unroll
      for (int dj = 0; dj < 8; ++dj)
        #pragma unroll
        for (int qi = 0; qi < 2; ++qi)
          acc[qi][dj] = __builtin_amdgcn_mfma_f32_16x16x32_bf16(
              pa[qi], vb[dj], acc[qi][dj], 0, 0, 0);

      if (more) {
        #pragma unroll
        for (int kj = 0; kj < 2; ++kj)
          #pragma unroll
          for (int ks = 0; ks < 4; ++ks)
            kb[kj][ks] = kbn[kj][ks];
      }
    }
  }

  // ---- per-wave l reduction across the 16 lo-lanes ----
  #pragma unroll
  for (int qi = 0; qi < 2; ++qi)
    #pragma unroll
    for (int r = 0; r < 4; ++r) {
      float lv = lrow[qi][r];
      lv += __shfl_xor(lv, 1);
      lv += __shfl_xor(lv, 2);
      lv += __shfl_xor(lv, 4);
      lv += __shfl_xor(lv, 8);
      lrow[qi][r] = lv;
    }

  // ---- waves 1-3: publish partials ----
  if (wv > 0) {
    #pragma unroll
    for (int qi = 0; qi < 2; ++qi) {
      #pragma unroll
      for (int dj = 0; dj < 8; ++dj)
        #pragma unroll
        for (int rp = 0; rp < 2; ++rp) {
          u32 pk = (u32)f2b(acc[qi][dj][2*rp]) |
                   ((u32)f2b(acc[qi][dj][2*rp+1]) << 16);
          Pacc[wv-1][(qi*8 + dj)*2 + rp][lane] = pk;
        }
      #pragma unroll
      for (int r = 0; r < 4; ++r)
        if (lo == 0) Lacc[wv-1][(qi*4 + r)*4 + hi] = lrow[qi][r];
    }
  }
  __syncthreads();
  if (wv > 0) return;

  // ---- wave 0: sum partials, gate, write yb ----
  #pragma unroll
  for (int qi = 0; qi < 2; ++qi) {
    #pragma unroll
    for (int dj = 0; dj < 8; ++dj)
      #pragma unroll
      for (int rp = 0; rp < 2; ++rp) {
        #pragma unroll
        for (int w = 0; w < 3; ++w) {
          u32 pk = Pacc[w][(qi*8 + dj)*2 + rp][lane];
          acc[qi][dj][2*rp]   += b2f((u16)(pk & 0xffff));
          acc[qi][dj][2*rp+1] += b2f((u16)(pk >> 16));
        }
      }
    #pragma unroll
    for (int r = 0; r < 4; ++r)
      #pragma unroll
      for (int w = 0; w < 3; ++w)
        lrow[qi][r] += Lacc[w][(qi*4 + r)*4 + hi];
  }

  #pragma unroll
  for (int qi = 0; qi < 2; ++qi)
    #pragma unroll
    for (int r = 0; r < 4; ++r) {
      int trow = t0w + qi*16 + hi*4 + r;
      size_t bt = (size_t)b*T_ + trow;
      float dotg = 0.f;
      #pragma unroll
      for (int jj = 0; jj < 12; ++jj)
        dotg += x[bt*E_ + jj]*Wg[h*12 + jj];
      float g = 1.f/(1.f + __expf(-dotg));
      float coef = g / lrow[qi][r];
      #pragma unroll
      for (int dj = 0; dj < 8; ++dj)
        yb[bt*E_ + h*D_ + dj*16 + lo] = f2b(acc[qi][dj][r]*coef);
    }
}

// ---------------------------------------------------------------------------
extern "C" void kernel_launch(void* const* d_in, const int* in_sizes, int n_in,
                              void* d_out, int out_size, void* d_ws, size_t ws_size,
                              hipStream_t stream) {
  const float* x    = (const float*)d_in[0];
  const float* v1   = (const float*)d_in[1];
  const float* Wq   = (const float*)d_in[2];
  const float* Wk   = (const float*)d_in[3];
  const float* Wv   = (const float*)d_in[4];
  const float* lamb = (const float*)d_in[5];
  const float* Wo   = (const float*)d_in[6];
  const float* Wg   = (const float*)d_in[7];
  float* out = (float*)d_out;

  // workspace layout (u16 units for bf16 buffers)
  u16* qkvb = (u16*)d_ws;                  // 8192*1024
  u16* qn   = qkvb + (size_t)M_*1024;
  u16* kn   = qn   + (size_t)M_*E_;
  u16* vn   = kn   + (size_t)M_*D_;
  u16* kfr  = vn   + (size_t)M_*D_;        // fragment-major K, M_*D_
  u16* vfr  = kfr  + (size_t)M_*D_;        // fragment-major V, M_*D_
  u16* yb   = vfr  + (size_t)M_*D_;
  float* cosT = (float*)(yb + (size_t)M_*E_);
  float* sinT = cosT + T_*64;

  k_rope_tables<<<T_, 64, 0, stream>>>(cosT, sinT);

  // fused QKV projection: y-blocks 0..5 = Wq, 6 = Wk, 7 = Wv
  k_gemm<0><<<dim3(M_/128, 8), 256, 0, stream>>>(
      x, Wq, Wk, Wv, 6, qkvb, 1024, 1);

  k_vmix_norm_rope<<<dim3(M_, 8), 128, 0, stream>>>(qkvb, v1, lamb, cosT, sinT,
                                                    qn, kn, vn);
  k_pack_frags<<<dim3(T_/32, B_), 256, 0, stream>>>(kn, vn, kfr, vfr);

  k_attn_mfma<<<B_*H_*(T_/32), 256, 0, stream>>>(qn, kfr, vfr, x, Wg, yb);

  k_gemm<1><<<dim3(M_/128, 6), 256, 0, stream>>>(
      yb, Wo, Wo, Wo, 6, out, 768, 0);

  hipMemcpyAsync(out + (size_t)M_*E_, v1, (size_t)M_*D_*sizeof(float),
                 hipMemcpyDeviceToDevice, stream);
}